// Round 2
// baseline (1892.973 us; speedup 1.0000x reference)
//
#include <hip/hip_runtime.h>

#define HID 32
#define NATOMS 250000
#define NPAIRS 4000000
#define MAXNEI 16
#define NMOL 2000
#define MAXATOMS 128
#define FEAT 8

__device__ __forceinline__ float sigmoidf_(float x) { return 1.f / (1.f + __expf(-x)); }
__device__ __forceinline__ float tanhf_(float x) {
    float e = __expf(2.f * x);
    return 1.f - 2.f / (e + 1.f);
}

// GRU update for one atom spread across 32 lanes (lane = output channel j).
// aggj/hj are this lane's channel of agg/h. Weight loads are coalesced 128B
// rows, L1-resident (24 KB total reused by every wave).
__device__ __forceinline__ float gru_update(float aggj, float hj, int j,
        const float* __restrict__ Wz, const float* __restrict__ Wr,
        const float* __restrict__ Whh, const float* __restrict__ bz,
        const float* __restrict__ br, const float* __restrict__ bh) {
    float accz = bz[j], accr = br[j];
#pragma unroll
    for (int k = 0; k < HID; k++) {
        float xk = __shfl(aggj, k, 32);
        accz = fmaf(xk, Wz[k * HID + j], accz);
        accr = fmaf(xk, Wr[k * HID + j], accr);
    }
#pragma unroll
    for (int k = 0; k < HID; k++) {
        float xk = __shfl(hj, k, 32);
        accz = fmaf(xk, Wz[(HID + k) * HID + j], accz);
        accr = fmaf(xk, Wr[(HID + k) * HID + j], accr);
    }
    float z = sigmoidf_(accz);
    float r = sigmoidf_(accr);
    float rh = r * hj;
    float acch = bh[j];
#pragma unroll
    for (int k = 0; k < HID; k++) {
        float xk = __shfl(aggj, k, 32);
        acch = fmaf(xk, Whh[k * HID + j], acch);
    }
#pragma unroll
    for (int k = 0; k < HID; k++) {
        float xk = __shfl(rh, k, 32);
        acch = fmaf(xk, Whh[(HID + k) * HID + j], acch);
    }
    return (1.f - z) * hj + z * tanhf_(acch);
}

// h1 = GRU0(h0 = tf@Wia, agg0 = (sum relu(edge@Wib))@Wh)
// 8 atoms per 256-thread block; 32 lanes per atom.
__global__ __launch_bounds__(256) void k_init_gru(
        const float* __restrict__ tf, const float* __restrict__ fdg,
        const float* __restrict__ rij, const int* __restrict__ bsc,
        const float* __restrict__ Wia, const float* __restrict__ Wib,
        const float* __restrict__ Wh,
        const float* __restrict__ Wz, const float* __restrict__ Wr,
        const float* __restrict__ Whh, const float* __restrict__ bz,
        const float* __restrict__ br, const float* __restrict__ bh,
        float* __restrict__ hout) {
    __shared__ float lbuf[8][MAXNEI][12];   // [group][nei][e0..e7, rij, valid, pad2]
    int grp = threadIdx.x >> 5;
    int j = threadIdx.x & 31;
    int gid = blockIdx.x * 8 + grp;         // NATOMS % 8 == 0: always valid

    int myidx = (j < MAXNEI) ? bsc[gid * MAXNEI + j] : 0;

    // cooperative edge-row load: lane (2n, 2n+1) load the two float4 halves of row n
    int n_l = j >> 1, half = j & 1;
    int idxn = __shfl(myidx, n_l, 32);
    size_t p_l = (idxn > 0) ? (size_t)(idxn - 1) : 0;
    float4 v = *(const float4*)&fdg[p_l * FEAT + half * 4];
    size_t pr = (myidx > 0) ? (size_t)(myidx - 1) : 0;
    float rv = rij[pr];

    // h0[gid][j]
    float hj = 0.f;
#pragma unroll
    for (int k = 0; k < FEAT; k++) hj = fmaf(tf[gid * FEAT + k], Wia[k * HID + j], hj);

    // W_i_b column j
    float wib[9];
#pragma unroll
    for (int k = 0; k < 9; k++) wib[k] = Wib[k * HID + j];

    *(float4*)&lbuf[grp][n_l][half * 4] = v;
    if (j < MAXNEI) {
        lbuf[grp][j][8] = rv;
        lbuf[grp][j][9] = (myidx > 0) ? 1.f : 0.f;
    }
    __syncthreads();   // all 256 threads always reach here

    float aggE = 0.f;
#pragma unroll
    for (int n = 0; n < MAXNEI; n++) {
        const float* row = lbuf[grp][n];
        float acc = row[8] * wib[8];
#pragma unroll
        for (int k = 0; k < FEAT; k++) acc = fmaf(row[k], wib[k], acc);
        aggE += row[9] * fmaxf(acc, 0.f);
    }

    float aggj = 0.f;
#pragma unroll
    for (int k = 0; k < HID; k++)
        aggj = fmaf(__shfl(aggE, k, 32), Wh[k * HID + j], aggj);

    float hn = gru_update(aggj, hj, j, Wz, Wr, Whh, bz, br, bh);
    hout[(size_t)gid * HID + j] = hn;
}

// h_next = GRU_d(h, agg = (sum_n h[su]+h[sul]) @ Wh); reads hin, writes hout.
__global__ __launch_bounds__(256) void k_agg_gru(
        const float* __restrict__ hin, const int* __restrict__ bsc,
        const int* __restrict__ su, const int* __restrict__ sul,
        const float* __restrict__ Wh,
        const float* __restrict__ Wz, const float* __restrict__ Wr,
        const float* __restrict__ Whh, const float* __restrict__ bz,
        const float* __restrict__ br, const float* __restrict__ bh,
        float* __restrict__ hout) {
    int grp = threadIdx.x >> 5;
    int j = threadIdx.x & 31;
    int gid = blockIdx.x * 8 + grp;

    int myidx = (j < MAXNEI) ? bsc[gid * MAXNEI + j] : 0;
    size_t p = (myidx > 0) ? (size_t)(myidx - 1) : 0;
    int a1 = su[p];
    int a2 = sul[p];
    float valid = (myidx > 0) ? 1.f : 0.f;

    float hj = hin[(size_t)gid * HID + j];

    float aggE = 0.f;
#pragma unroll
    for (int n = 0; n < MAXNEI; n++) {
        int b1 = __shfl(a1, n, 32);
        int b2 = __shfl(a2, n, 32);
        float m = __shfl(valid, n, 32);
        aggE += m * (hin[(size_t)b1 * HID + j] + hin[(size_t)b2 * HID + j]);
    }

    float aggj = 0.f;
#pragma unroll
    for (int k = 0; k < HID; k++)
        aggj = fmaf(__shfl(aggE, k, 32), Wh[k * HID + j], aggj);

    float hn = gru_update(aggj, hj, j, Wz, Wr, Whh, bz, br, bh);
    hout[(size_t)gid * HID + j] = hn;
}

// mol_vecs[m][j] = sum_i (l_scope[m][i] ? h[idx-1][j] : 0)
__global__ __launch_bounds__(256) void k_mol(
        const float* __restrict__ h, const int* __restrict__ lsc,
        float* __restrict__ out) {
    int m = blockIdx.x;
    int g = threadIdx.x >> 5;
    int j = threadIdx.x & 31;
    float acc = 0.f;
    for (int i = g; i < MAXATOMS; i += 8) {
        int idx = lsc[m * MAXATOMS + i];
        if (idx > 0) acc += h[(size_t)(idx - 1) * HID + j];
    }
    __shared__ float red[8][33];
    red[g][j] = acc;
    __syncthreads();
    if (g == 0) {
        float s = red[0][j] + red[1][j] + red[2][j] + red[3][j]
                + red[4][j] + red[5][j] + red[6][j] + red[7][j];
        out[m * HID + j] = s;
    }
}

extern "C" void kernel_launch(void* const* d_in, const int* in_sizes, int n_in,
                              void* d_out, int out_size, void* d_ws, size_t ws_size,
                              hipStream_t stream) {
    (void)in_sizes; (void)n_in; (void)out_size; (void)ws_size;
    const float* tf  = (const float*)d_in[0];
    const float* fdg = (const float*)d_in[1];
    const float* rij = (const float*)d_in[2];
    const int*   bsc = (const int*)d_in[3];
    const int*   lsc = (const int*)d_in[4];
    const int*   su  = (const int*)d_in[5];
    const int*   sul = (const int*)d_in[6];
    const float* Wia = (const float*)d_in[7];
    const float* Wib = (const float*)d_in[8];
    const float* Wh  = (const float*)d_in[9];
    const float* gWz = (const float*)d_in[10];
    const float* gWr = (const float*)d_in[11];
    const float* gWh = (const float*)d_in[12];
    const float* gbz = (const float*)d_in[13];
    const float* gbr = (const float*)d_in[14];
    const float* gbh = (const float*)d_in[15];
    float* out = (float*)d_out;

    float* hA = (float*)d_ws;                     // 32 MB
    float* hB = hA + (size_t)NATOMS * HID;        // 32 MB

    dim3 grid(NATOMS / 8);   // 31250, exact

    // depth 0: edges -> agg0, h0 -> h1 (into hA)
    k_init_gru<<<grid, 256, 0, stream>>>(tf, fdg, rij, bsc, Wia, Wib, Wh,
        gWz, gWr, gWh, gbz, gbr, gbh, hA);
    // depth 1: hA -> hB
    k_agg_gru<<<grid, 256, 0, stream>>>(hA, bsc, su, sul, Wh,
        gWz + 2 * HID * HID, gWr + 2 * HID * HID, gWh + 2 * HID * HID,
        gbz + HID, gbr + HID, gbh + HID, hB);
    // depth 2: hB -> hA
    k_agg_gru<<<grid, 256, 0, stream>>>(hB, bsc, su, sul, Wh,
        gWz + 4 * HID * HID, gWr + 4 * HID * HID, gWh + 4 * HID * HID,
        gbz + 2 * HID, gbr + 2 * HID, gbh + 2 * HID, hA);

    k_mol<<<NMOL, 256, 0, stream>>>(hA, lsc, out);
}

// Round 3
// 971.892 us; speedup vs baseline: 1.9477x; 1.9477x over previous
//
#include <hip/hip_runtime.h>

#define HID 32
#define NATOMS 250000
#define NPAIRS 4000000
#define MAXNEI 16
#define NMOL 2000
#define MAXATOMS 128
#define FEAT 8
#define GBLK 128

__device__ __forceinline__ float sigmoidf_(float x) { return 1.f / (1.f + __expf(-x)); }
__device__ __forceinline__ float tanhfast_(float x) {
    float e = __expf(2.f * x);
    return 1.f - 2.f / (e + 1.f);
}

// h0 = tf @ W_i_a ; agg0 = (sum_n relu(edge_in[idx_n-1] @ W_i_b)) @ W_h
// 8 atoms / 256-thread block, 32 lanes per atom. Edge rows loaded
// cooperatively in ONE float4 sweep (lane 2n,2n+1 load the halves of row n).
__global__ __launch_bounds__(256) void k_init(
        const float* __restrict__ tf, const float* __restrict__ fdg,
        const float* __restrict__ rij, const int* __restrict__ bsc,
        const float* __restrict__ Wia, const float* __restrict__ Wib,
        const float* __restrict__ Wh,
        float* __restrict__ h, float* __restrict__ agg) {
    __shared__ float lbuf[8][MAXNEI][12];   // [grp][nei][e0..e7, rij, valid, pad2]
    int grp = threadIdx.x >> 5;
    int j = threadIdx.x & 31;
    int gid = blockIdx.x * 8 + grp;         // NATOMS % 8 == 0

    int myidx = (j < MAXNEI) ? bsc[gid * MAXNEI + j] : 0;

    int n_l = j >> 1, half = j & 1;
    int idxn = __shfl(myidx, n_l, 32);
    size_t p_l = (idxn > 0) ? (size_t)(idxn - 1) : 0;
    float4 v = *(const float4*)&fdg[p_l * FEAT + half * 4];
    size_t pr = (myidx > 0) ? (size_t)(myidx - 1) : 0;
    float rv = rij[pr];

    float hj = 0.f;
#pragma unroll
    for (int k = 0; k < FEAT; k++) hj = fmaf(tf[gid * FEAT + k], Wia[k * HID + j], hj);

    float wib[9];
#pragma unroll
    for (int k = 0; k < 9; k++) wib[k] = Wib[k * HID + j];

    *(float4*)&lbuf[grp][n_l][half * 4] = v;
    if (j < MAXNEI) {
        lbuf[grp][j][8] = rv;
        lbuf[grp][j][9] = (myidx > 0) ? 1.f : 0.f;
    }
    __syncthreads();   // all threads always reach

    float aggE = 0.f;
#pragma unroll
    for (int n = 0; n < MAXNEI; n++) {
        const float* row = lbuf[grp][n];
        float acc = row[8] * wib[8];
#pragma unroll
        for (int k = 0; k < FEAT; k++) acc = fmaf(row[k], wib[k], acc);
        aggE += row[9] * fmaxf(acc, 0.f);
    }

    float aggj = 0.f;
#pragma unroll
    for (int k = 0; k < HID; k++)
        aggj = fmaf(__shfl(aggE, k, 32), Wh[k * HID + j], aggj);

    h[(size_t)gid * HID + j] = hj;
    agg[(size_t)gid * HID + j] = aggj;
}

// agg = (sum_n h[su]+h[sul]) @ Wh.  32 lanes/atom; float4 sweep gather:
// lane l = rsel*8 + c owns row-slot rsel (0..3) and column-quad c (0..7).
// 8 sweeps x 1 independent float4 load each -> 8 loads in flight per lane.
__global__ __launch_bounds__(256) void k_agg(
        const float* __restrict__ hin, const int* __restrict__ bsc,
        const int* __restrict__ su, const int* __restrict__ sul,
        const float* __restrict__ Wh, float* __restrict__ agg) {
    int grp = threadIdx.x >> 5;
    int j = threadIdx.x & 31;
    int gid = blockIdx.x * 8 + grp;

    int myidx = (j < MAXNEI) ? bsc[gid * MAXNEI + j] : 0;
    size_t p = (myidx > 0) ? (size_t)(myidx - 1) : 0;
    int a1 = su[p];
    int a2 = sul[p];
    float valid = (myidx > 0) ? 1.f : 0.f;

    int rsel = (j >> 3) & 3;   // row-within-sweep
    int c = j & 7;             // column quad

    float4 acc = make_float4(0.f, 0.f, 0.f, 0.f);
#pragma unroll
    for (int s = 0; s < 8; s++) {
        int src = (4 * s + rsel) & 15;                 // source lane (0..15)
        int row = __shfl((s < 4) ? a1 : a2, src, 32);  // s compile-time
        float m = __shfl(valid, src, 32);
        float4 v = *(const float4*)&hin[(size_t)row * HID + c * 4];
        acc.x = fmaf(m, v.x, acc.x);
        acc.y = fmaf(m, v.y, acc.y);
        acc.z = fmaf(m, v.z, acc.z);
        acc.w = fmaf(m, v.w, acc.w);
    }
    // reduce the 4 row-slots that share a column quad (lanes l, l^8, l^16)
#pragma unroll
    for (int mlane = 8; mlane <= 16; mlane <<= 1) {
        acc.x += __shfl_xor(acc.x, mlane, 32);
        acc.y += __shfl_xor(acc.y, mlane, 32);
        acc.z += __shfl_xor(acc.z, mlane, 32);
        acc.w += __shfl_xor(acc.w, mlane, 32);
    }
    // out_j = sum_k aggE_k * Wh[k][j]; aggE_k lives in component k&3 of lane k>>2
    float out = 0.f;
#pragma unroll
    for (int k = 0; k < HID; k++) {
        float comp = ((k & 3) == 0) ? acc.x : ((k & 3) == 1) ? acc.y
                   : ((k & 3) == 2) ? acc.z : acc.w;       // compile-time select
        float aggk = __shfl(comp, k >> 2, 32);
        out = fmaf(aggk, Wh[k * HID + j], out);
    }
    agg[(size_t)gid * HID + j] = out;
}

// GRU update, one thread per atom; xh row in LDS; weight addresses are
// wave-uniform -> scalar loads. Updates h in place.
__global__ __launch_bounds__(GBLK) void k_gru(
        float* __restrict__ h, const float* __restrict__ agg,
        const float* __restrict__ Wz, const float* __restrict__ Wr,
        const float* __restrict__ Whh, const float* __restrict__ bz,
        const float* __restrict__ br, const float* __restrict__ bh) {
    __shared__ float xh[GBLK * 65];
    int tid = threadIdx.x;
    int a = blockIdx.x * GBLK + tid;
    if (a >= NATOMS) return;   // no __syncthreads below
    float* myxh = &xh[tid * 65];

    float hreg[HID];
#pragma unroll
    for (int k = 0; k < HID; k += 4) {
        float4 av = *(const float4*)&agg[(size_t)a * HID + k];
        myxh[k] = av.x; myxh[k + 1] = av.y; myxh[k + 2] = av.z; myxh[k + 3] = av.w;
        float4 hv = *(const float4*)&h[(size_t)a * HID + k];
        hreg[k] = hv.x; hreg[k + 1] = hv.y; hreg[k + 2] = hv.z; hreg[k + 3] = hv.w;
        myxh[32 + k] = hv.x; myxh[33 + k] = hv.y; myxh[34 + k] = hv.z; myxh[35 + k] = hv.w;
    }

    float accz[HID], accr[HID];
#pragma unroll
    for (int jj = 0; jj < HID; jj++) { accz[jj] = bz[jj]; accr[jj] = br[jj]; }

    for (int k = 0; k < 2 * HID; k++) {
        float xk = myxh[k];
#pragma unroll
        for (int jj = 0; jj < HID; jj++) {
            accz[jj] = fmaf(xk, Wz[k * HID + jj], accz[jj]);
            accr[jj] = fmaf(xk, Wr[k * HID + jj], accr[jj]);
        }
    }

    float z[HID];
#pragma unroll
    for (int jj = 0; jj < HID; jj++) {
        z[jj] = sigmoidf_(accz[jj]);
        float r = sigmoidf_(accr[jj]);
        myxh[32 + jj] = r * hreg[jj];
    }

    float acch[HID];
#pragma unroll
    for (int jj = 0; jj < HID; jj++) acch[jj] = bh[jj];
    for (int k = 0; k < 2 * HID; k++) {
        float xk = myxh[k];
#pragma unroll
        for (int jj = 0; jj < HID; jj++) acch[jj] = fmaf(xk, Whh[k * HID + jj], acch[jj]);
    }

#pragma unroll
    for (int jj = 0; jj < HID; jj += 4) {
        float4 o;
        o.x = (1.f - z[jj    ]) * hreg[jj    ] + z[jj    ] * tanhfast_(acch[jj    ]);
        o.y = (1.f - z[jj + 1]) * hreg[jj + 1] + z[jj + 1] * tanhfast_(acch[jj + 1]);
        o.z = (1.f - z[jj + 2]) * hreg[jj + 2] + z[jj + 2] * tanhfast_(acch[jj + 2]);
        o.w = (1.f - z[jj + 3]) * hreg[jj + 3] + z[jj + 3] * tanhfast_(acch[jj + 3]);
        *(float4*)&h[(size_t)a * HID + jj] = o;
    }
}

__global__ __launch_bounds__(256) void k_mol(
        const float* __restrict__ h, const int* __restrict__ lsc,
        float* __restrict__ out) {
    int m = blockIdx.x;
    int g = threadIdx.x >> 5;
    int j = threadIdx.x & 31;
    float acc = 0.f;
    for (int i = g; i < MAXATOMS; i += 8) {
        int idx = lsc[m * MAXATOMS + i];
        if (idx > 0) acc += h[(size_t)(idx - 1) * HID + j];
    }
    __shared__ float red[8][33];
    red[g][j] = acc;
    __syncthreads();
    if (g == 0) {
        float s = red[0][j] + red[1][j] + red[2][j] + red[3][j]
                + red[4][j] + red[5][j] + red[6][j] + red[7][j];
        out[m * HID + j] = s;
    }
}

extern "C" void kernel_launch(void* const* d_in, const int* in_sizes, int n_in,
                              void* d_out, int out_size, void* d_ws, size_t ws_size,
                              hipStream_t stream) {
    (void)in_sizes; (void)n_in; (void)out_size; (void)ws_size;
    const float* tf  = (const float*)d_in[0];
    const float* fdg = (const float*)d_in[1];
    const float* rij = (const float*)d_in[2];
    const int*   bsc = (const int*)d_in[3];
    const int*   lsc = (const int*)d_in[4];
    const int*   su  = (const int*)d_in[5];
    const int*   sul = (const int*)d_in[6];
    const float* Wia = (const float*)d_in[7];
    const float* Wib = (const float*)d_in[8];
    const float* Wh  = (const float*)d_in[9];
    const float* gWz = (const float*)d_in[10];
    const float* gWr = (const float*)d_in[11];
    const float* gWh = (const float*)d_in[12];
    const float* gbz = (const float*)d_in[13];
    const float* gbr = (const float*)d_in[14];
    const float* gbh = (const float*)d_in[15];
    float* out = (float*)d_out;

    float* h   = (float*)d_ws;                     // 32 MB
    float* agg = h + (size_t)NATOMS * HID;         // 32 MB

    dim3 agrid(NATOMS / 8);   // exact

    k_init<<<agrid, 256, 0, stream>>>(tf, fdg, rij, bsc, Wia, Wib, Wh, h, agg);
    for (int d = 0; d < 3; d++) {
        k_gru<<<(NATOMS + GBLK - 1) / GBLK, GBLK, 0, stream>>>(
            h, agg, gWz + d * 2 * HID * HID, gWr + d * 2 * HID * HID,
            gWh + d * 2 * HID * HID, gbz + d * HID, gbr + d * HID, gbh + d * HID);
        if (d < 2) {
            k_agg<<<agrid, 256, 0, stream>>>(h, bsc, su, sul, Wh, agg);
        }
    }
    k_mol<<<NMOL, 256, 0, stream>>>(h, lsc, out);
}

// Round 4
// 819.007 us; speedup vs baseline: 2.3113x; 1.1867x over previous
//
#include <hip/hip_runtime.h>

#define HID 32
#define NATOMS 250000
#define NPAIRS 4000000
#define MAXNEI 16
#define NMOL 2000
#define MAXATOMS 128
#define FEAT 8
#define GBLK 128

typedef unsigned short ushort_t;
typedef unsigned int uint_t;

__device__ __forceinline__ float sigmoidf_(float x) { return 1.f / (1.f + __expf(-x)); }
__device__ __forceinline__ float tanhfast_(float x) {
    float e = __expf(2.f * x);
    return 1.f - 2.f / (e + 1.f);
}
__device__ __forceinline__ ushort_t f2bf(float f) {   // RNE
    uint_t u = __float_as_uint(f);
    u = (u + 0x7fffu + ((u >> 16) & 1u)) >> 16;
    return (ushort_t)u;
}

// h0 = tf@Wia ; agg0 = (sum relu(edge@Wib))@Wh ; also builds srcs table and
// zeroes hbf dummy row. 2 atoms per 32-lane group, 8 groups per block.
__global__ __launch_bounds__(256) void k_init(
        const float* __restrict__ tf, const float* __restrict__ fdg,
        const float* __restrict__ rij, const int* __restrict__ bsc,
        const int* __restrict__ su, const int* __restrict__ sul,
        const float* __restrict__ Wia, const float* __restrict__ Wib,
        const float* __restrict__ Wh,
        float* __restrict__ h, float* __restrict__ agg,
        int* __restrict__ srcs, ushort_t* __restrict__ hbf) {
    __shared__ float lbuf[8][2][MAXNEI][12];  // [grp][atom][nei][e0..7, rij, valid, pad]
    int grp = threadIdx.x >> 5;
    int j = threadIdx.x & 31;
    int ja = j >> 4;              // which atom this lane serves for slot duty
    int n = j & 15;               // neighbor slot
    int gid0 = (blockIdx.x * 8 + grp) * 2;   // grid 15625 -> gid0 in [0,250000) exact
    int gidja = gid0 + ja;

    int myidx = bsc[gidja * MAXNEI + n];
    int p = (myidx > 0) ? (myidx - 1) : 0;
    float valid = (myidx > 0) ? 1.f : 0.f;

    if (srcs) {   // kernel-arg-uniform branch
        int s1 = (myidx > 0) ? su[p] : NATOMS;
        int s2 = (myidx > 0) ? sul[p] : NATOMS;
        srcs[gidja * 32 + n] = s1;
        srcs[gidja * 32 + 16 + n] = s2;
    }
    if (hbf && blockIdx.x == 0 && threadIdx.x < HID)
        hbf[(size_t)NATOMS * HID + threadIdx.x] = 0;

    float rv = rij[p];

    // two cooperative edge-row sweeps (one per atom), independent loads
    float4 v0, v1;
    {
        int m = j >> 1, half = (j & 1) * 4;
        int p0 = __shfl(p, m, 32);          // lane m holds atom0 slot m
        int p1 = __shfl(p, 16 + m, 32);     // lane 16+m holds atom1 slot m
        v0 = *(const float4*)&fdg[(size_t)p0 * FEAT + half];
        v1 = *(const float4*)&fdg[(size_t)p1 * FEAT + half];
        *(float4*)&lbuf[grp][0][m][half] = v0;
        *(float4*)&lbuf[grp][1][m][half] = v1;
    }
    lbuf[grp][ja][n][8] = rv;
    lbuf[grp][ja][n][9] = valid;

    float wib[9];
#pragma unroll
    for (int k = 0; k < 9; k++) wib[k] = Wib[k * HID + j];

    __syncthreads();   // all 256 threads always reach

    float aggE[2];
#pragma unroll
    for (int a = 0; a < 2; a++) {
        float e = 0.f;
#pragma unroll
        for (int nn = 0; nn < MAXNEI; nn++) {
            const float* row = lbuf[grp][a][nn];
            float acc = row[8] * wib[8];
#pragma unroll
            for (int k = 0; k < FEAT; k++) acc = fmaf(row[k], wib[k], acc);
            e += row[9] * fmaxf(acc, 0.f);
        }
        aggE[a] = e;
    }

    // h0 rows for both atoms
    float hj0 = 0.f, hj1 = 0.f;
#pragma unroll
    for (int k = 0; k < FEAT; k++) {
        hj0 = fmaf(tf[(size_t)gid0 * FEAT + k], Wia[k * HID + j], hj0);
        hj1 = fmaf(tf[(size_t)(gid0 + 1) * FEAT + k], Wia[k * HID + j], hj1);
    }

    float o0 = 0.f, o1 = 0.f;
#pragma unroll
    for (int k = 0; k < HID; k++) {
        float wv = Wh[k * HID + j];
        o0 = fmaf(__shfl(aggE[0], k, 32), wv, o0);
        o1 = fmaf(__shfl(aggE[1], k, 32), wv, o1);
    }
    h[(size_t)gid0 * HID + j] = hj0;
    h[(size_t)(gid0 + 1) * HID + j] = hj1;
    agg[(size_t)gid0 * HID + j] = o0;
    agg[(size_t)(gid0 + 1) * HID + j] = o1;
}

// GRU update, one thread per atom; xh in LDS (runtime-k broadcast reads);
// weights wave-uniform -> scalar loads. Writes fp32 h and optional bf16 mirror.
__global__ __launch_bounds__(GBLK) void k_gru(
        float* __restrict__ h, ushort_t* __restrict__ hbf,
        const float* __restrict__ agg,
        const float* __restrict__ Wz, const float* __restrict__ Wr,
        const float* __restrict__ Whh, const float* __restrict__ bz,
        const float* __restrict__ br, const float* __restrict__ bh) {
    __shared__ float xh[GBLK][65];
    int tid = threadIdx.x;
    int a = blockIdx.x * GBLK + tid;
    if (a >= NATOMS) return;   // no __syncthreads below
    float* myxh = xh[tid];

    float hreg[HID];
#pragma unroll
    for (int k = 0; k < HID; k += 4) {
        float4 av = *(const float4*)&agg[(size_t)a * HID + k];
        myxh[k] = av.x; myxh[k + 1] = av.y; myxh[k + 2] = av.z; myxh[k + 3] = av.w;
        float4 hv = *(const float4*)&h[(size_t)a * HID + k];
        hreg[k] = hv.x; hreg[k + 1] = hv.y; hreg[k + 2] = hv.z; hreg[k + 3] = hv.w;
        myxh[32 + k] = hv.x; myxh[33 + k] = hv.y; myxh[34 + k] = hv.z; myxh[35 + k] = hv.w;
    }

    float z[HID];
    {   // z pass
        float acc[HID];
#pragma unroll
        for (int jj = 0; jj < HID; jj++) acc[jj] = bz[jj];
        for (int k = 0; k < 2 * HID; k++) {
            float xk = myxh[k];
#pragma unroll
            for (int jj = 0; jj < HID; jj++) acc[jj] = fmaf(xk, Wz[k * HID + jj], acc[jj]);
        }
#pragma unroll
        for (int jj = 0; jj < HID; jj++) z[jj] = sigmoidf_(acc[jj]);
    }
    {   // r pass -> overwrite xh[32..63] with r*h
        float acc[HID];
#pragma unroll
        for (int jj = 0; jj < HID; jj++) acc[jj] = br[jj];
        for (int k = 0; k < 2 * HID; k++) {
            float xk = myxh[k];
#pragma unroll
            for (int jj = 0; jj < HID; jj++) acc[jj] = fmaf(xk, Wr[k * HID + jj], acc[jj]);
        }
#pragma unroll
        for (int jj = 0; jj < HID; jj++) myxh[32 + jj] = sigmoidf_(acc[jj]) * hreg[jj];
    }
    float o[HID];
    {   // candidate pass
        float acc[HID];
#pragma unroll
        for (int jj = 0; jj < HID; jj++) acc[jj] = bh[jj];
        for (int k = 0; k < 2 * HID; k++) {
            float xk = myxh[k];
#pragma unroll
            for (int jj = 0; jj < HID; jj++) acc[jj] = fmaf(xk, Whh[k * HID + jj], acc[jj]);
        }
#pragma unroll
        for (int jj = 0; jj < HID; jj++)
            o[jj] = (1.f - z[jj]) * hreg[jj] + z[jj] * tanhfast_(acc[jj]);
    }

#pragma unroll
    for (int jj = 0; jj < HID; jj += 4)
        *(float4*)&h[(size_t)a * HID + jj] = make_float4(o[jj], o[jj + 1], o[jj + 2], o[jj + 3]);

    if (hbf) {
        uint_t us[16];
#pragma unroll
        for (int jj = 0; jj < HID; jj += 2)
            us[jj >> 1] = (uint_t)f2bf(o[jj]) | ((uint_t)f2bf(o[jj + 1]) << 16);
        uint4* dst = (uint4*)(hbf + (size_t)a * HID);
#pragma unroll
        for (int q = 0; q < 4; q++)
            dst[q] = make_uint4(us[4 * q], us[4 * q + 1], us[4 * q + 2], us[4 * q + 3]);
    }
}

// agg = (sum of 32 gathered bf16 h rows) @ Wh. 2 atoms per 32-lane group;
// maskless via srcs table (invalid -> zero row NATOMS). 8 loads in flight/lane.
__global__ __launch_bounds__(256) void k_agg(
        const ushort_t* __restrict__ hbf, const int* __restrict__ srcs,
        const float* __restrict__ Wh, float* __restrict__ agg) {
    int grp = threadIdx.x >> 5;
    int j = threadIdx.x & 31;
    int gid0 = (blockIdx.x * 8 + grp) * 2;

    int s0 = srcs[(size_t)gid0 * 32 + j];
    int s1 = srcs[(size_t)(gid0 + 1) * 32 + j];

    int rslot = j >> 2;   // 0..7
    int c = j & 3;        // 16B quad within 64B row

    uint4 v0[4], v1[4];
#pragma unroll
    for (int s = 0; s < 4; s++) {
        int rs = s * 8 + rslot;
        int r0 = __shfl(s0, rs, 32);
        int r1 = __shfl(s1, rs, 32);
        v0[s] = ((const uint4*)(hbf + (size_t)r0 * HID))[c];
        v1[s] = ((const uint4*)(hbf + (size_t)r1 * HID))[c];
    }

    float acc0[8], acc1[8];
#pragma unroll
    for (int e = 0; e < 8; e++) { acc0[e] = 0.f; acc1[e] = 0.f; }
#pragma unroll
    for (int s = 0; s < 4; s++) {
        const uint_t* u0 = (const uint_t*)&v0[s];
        const uint_t* u1 = (const uint_t*)&v1[s];
#pragma unroll
        for (int e = 0; e < 8; e++) {
            uint_t w0 = u0[e >> 1], w1 = u1[e >> 1];
            acc0[e] += __uint_as_float((e & 1) ? (w0 & 0xffff0000u) : (w0 << 16));
            acc1[e] += __uint_as_float((e & 1) ? (w1 & 0xffff0000u) : (w1 << 16));
        }
    }
    // reduce across rslot (lane bits 2,3,4)
#pragma unroll
    for (int m = 4; m <= 16; m <<= 1) {
#pragma unroll
        for (int e = 0; e < 8; e++) {
            acc0[e] += __shfl_xor(acc0[e], m, 32);
            acc1[e] += __shfl_xor(acc1[e], m, 32);
        }
    }
    // lane with (l&3)==q holds quad q: aggE[q*8+e] = acc[e]
    float o0 = 0.f, o1 = 0.f;
#pragma unroll
    for (int k = 0; k < HID; k++) {
        float a0k = __shfl(acc0[k & 7], k >> 3, 32);
        float a1k = __shfl(acc1[k & 7], k >> 3, 32);
        float wv = Wh[k * HID + j];
        o0 = fmaf(a0k, wv, o0);
        o1 = fmaf(a1k, wv, o1);
    }
    agg[(size_t)gid0 * HID + j] = o0;
    agg[(size_t)(gid0 + 1) * HID + j] = o1;
}

// fallback (ws too small): round-3 fp32 masked gather version
__global__ __launch_bounds__(256) void k_agg_fb(
        const float* __restrict__ hin, const int* __restrict__ bsc,
        const int* __restrict__ su, const int* __restrict__ sul,
        const float* __restrict__ Wh, float* __restrict__ agg) {
    int grp = threadIdx.x >> 5;
    int j = threadIdx.x & 31;
    int gid = blockIdx.x * 8 + grp;

    int myidx = (j < MAXNEI) ? bsc[gid * MAXNEI + j] : 0;
    size_t p = (myidx > 0) ? (size_t)(myidx - 1) : 0;
    int a1 = su[p];
    int a2 = sul[p];
    float valid = (myidx > 0) ? 1.f : 0.f;

    int rsel = (j >> 3) & 3;
    int c = j & 7;
    float4 acc = make_float4(0.f, 0.f, 0.f, 0.f);
#pragma unroll
    for (int s = 0; s < 8; s++) {
        int src = (4 * s + rsel) & 15;
        int row = __shfl((s < 4) ? a1 : a2, src, 32);
        float m = __shfl(valid, src, 32);
        float4 v = *(const float4*)&hin[(size_t)row * HID + c * 4];
        acc.x = fmaf(m, v.x, acc.x); acc.y = fmaf(m, v.y, acc.y);
        acc.z = fmaf(m, v.z, acc.z); acc.w = fmaf(m, v.w, acc.w);
    }
#pragma unroll
    for (int mlane = 8; mlane <= 16; mlane <<= 1) {
        acc.x += __shfl_xor(acc.x, mlane, 32);
        acc.y += __shfl_xor(acc.y, mlane, 32);
        acc.z += __shfl_xor(acc.z, mlane, 32);
        acc.w += __shfl_xor(acc.w, mlane, 32);
    }
    float out = 0.f;
#pragma unroll
    for (int k = 0; k < HID; k++) {
        float comp = ((k & 3) == 0) ? acc.x : ((k & 3) == 1) ? acc.y
                   : ((k & 3) == 2) ? acc.z : acc.w;
        float aggk = __shfl(comp, k >> 2, 32);
        out = fmaf(aggk, Wh[k * HID + j], out);
    }
    agg[(size_t)gid * HID + j] = out;
}

__global__ __launch_bounds__(256) void k_mol(
        const float* __restrict__ h, const int* __restrict__ lsc,
        float* __restrict__ out) {
    int m = blockIdx.x;
    int g = threadIdx.x >> 5;
    int j = threadIdx.x & 31;
    float acc = 0.f;
    for (int i = g; i < MAXATOMS; i += 8) {
        int idx = lsc[m * MAXATOMS + i];
        if (idx > 0) acc += h[(size_t)(idx - 1) * HID + j];
    }
    __shared__ float red[8][33];
    red[g][j] = acc;
    __syncthreads();
    if (g == 0) {
        float s = red[0][j] + red[1][j] + red[2][j] + red[3][j]
                + red[4][j] + red[5][j] + red[6][j] + red[7][j];
        out[m * HID + j] = s;
    }
}

extern "C" void kernel_launch(void* const* d_in, const int* in_sizes, int n_in,
                              void* d_out, int out_size, void* d_ws, size_t ws_size,
                              hipStream_t stream) {
    (void)in_sizes; (void)n_in; (void)out_size;
    const float* tf  = (const float*)d_in[0];
    const float* fdg = (const float*)d_in[1];
    const float* rij = (const float*)d_in[2];
    const int*   bsc = (const int*)d_in[3];
    const int*   lsc = (const int*)d_in[4];
    const int*   su  = (const int*)d_in[5];
    const int*   sul = (const int*)d_in[6];
    const float* Wia = (const float*)d_in[7];
    const float* Wib = (const float*)d_in[8];
    const float* Wh  = (const float*)d_in[9];
    const float* gWz = (const float*)d_in[10];
    const float* gWr = (const float*)d_in[11];
    const float* gWh = (const float*)d_in[12];
    const float* gbz = (const float*)d_in[13];
    const float* gbr = (const float*)d_in[14];
    const float* gbh = (const float*)d_in[15];
    float* out = (float*)d_out;

    char* ws = (char*)d_ws;
    const size_t HBYTES = (size_t)NATOMS * HID * 4;                 // 32 MB
    const size_t HBFBYTES = ((size_t)(NATOMS + 1) * HID * 2 + 255) & ~(size_t)255;
    float* h   = (float*)ws;                                        // 32 MB
    float* agg = (float*)(ws + HBYTES);                             // 32 MB
    ushort_t* hbf = (ushort_t*)(ws + 2 * HBYTES);                   // ~16 MB
    int* srcs = (int*)(ws + 2 * HBYTES + HBFBYTES);                 // 32 MB
    const size_t NEED = 2 * HBYTES + HBFBYTES + (size_t)NATOMS * 32 * 4;
    bool fast = (ws_size >= NEED);
    if (!fast) { hbf = nullptr; srcs = nullptr; }

    dim3 igrid(NATOMS / 16);   // 15625, exact
    dim3 agrid(NATOMS / 8);    // for fallback k_agg_fb

    k_init<<<igrid, 256, 0, stream>>>(tf, fdg, rij, bsc, su, sul, Wia, Wib, Wh,
                                      h, agg, srcs, hbf);
    for (int d = 0; d < 3; d++) {
        ushort_t* hbf_w = (fast && d < 2) ? hbf : nullptr;
        k_gru<<<(NATOMS + GBLK - 1) / GBLK, GBLK, 0, stream>>>(
            h, hbf_w, agg, gWz + d * 2 * HID * HID, gWr + d * 2 * HID * HID,
            gWh + d * 2 * HID * HID, gbz + d * HID, gbr + d * HID, gbh + d * HID);
        if (d < 2) {
            if (fast)
                k_agg<<<igrid, 256, 0, stream>>>(hbf, srcs, Wh, agg);
            else
                k_agg_fb<<<agrid, 256, 0, stream>>>(h, bsc, su, sul, Wh, agg);
        }
    }
    k_mol<<<NMOL, 256, 0, stream>>>(h, lsc, out);
}

// Round 5
// 707.421 us; speedup vs baseline: 2.6759x; 1.1577x over previous
//
#include <hip/hip_runtime.h>

#define HID 32
#define NATOMS 250000
#define NPAIRS 4000000
#define MAXNEI 16
#define NMOL 2000
#define MAXATOMS 128
#define FEAT 8
#define GBLK 128

typedef unsigned short ushort_t;
typedef unsigned int uint_t;

__device__ __forceinline__ float sigmoidf_(float x) { return 1.f / (1.f + __expf(-x)); }
__device__ __forceinline__ float tanhfast_(float x) {
    float e = __expf(2.f * x);
    return 1.f - 2.f / (e + 1.f);
}
__device__ __forceinline__ ushort_t f2bf(float f) {   // RNE
    uint_t u = __float_as_uint(f);
    u = (u + 0x7fffu + ((u >> 16) & 1u)) >> 16;
    return (ushort_t)u;
}

// Pack per-pair sideband data into one 16B record so k_init's slot gather
// touches ONE cache line instead of three. Fully coalesced stream.
__global__ __launch_bounds__(256) void k_prep(
        const float* __restrict__ rij, const int* __restrict__ su,
        const int* __restrict__ sul, int4* __restrict__ rec) {
    int p = blockIdx.x * 256 + threadIdx.x;   // grid exact: NPAIRS/256
    rec[p] = make_int4(__float_as_int(rij[p]), su[p], sul[p], 0);
}

// h0 = tf@Wia ; agg0 = (sum relu(edge@Wib))@Wh ; builds srcs table; zeroes
// hbf dummy row. 2 atoms per 32-lane group, 8 groups per block.
__global__ __launch_bounds__(256) void k_init(
        const float* __restrict__ tf, const float* __restrict__ fdg,
        const float* __restrict__ rij, const int* __restrict__ bsc,
        const int* __restrict__ su, const int* __restrict__ sul,
        const int4* __restrict__ rec,
        const float* __restrict__ Wia, const float* __restrict__ Wib,
        const float* __restrict__ Wh,
        float* __restrict__ h, float* __restrict__ agg,
        int* __restrict__ srcs, ushort_t* __restrict__ hbf) {
    __shared__ float lbuf[8][2][MAXNEI][12];  // [grp][atom][nei][e0..7, rij, valid, pad]
    int grp = threadIdx.x >> 5;
    int j = threadIdx.x & 31;
    int ja = j >> 4;              // which atom this lane's slot belongs to
    int n = j & 15;               // neighbor slot
    int gid0 = (blockIdx.x * 8 + grp) * 2;   // grid 15625 -> exact
    int gidja = gid0 + ja;

    int myidx = bsc[gidja * MAXNEI + n];
    int p = (myidx > 0) ? (myidx - 1) : 0;
    float valid = (myidx > 0) ? 1.f : 0.f;

    float rv;
    int s1, s2;
    if (rec) {                                // kernel-arg-uniform branch
        int4 r = rec[p];                      // ONE line: rij+su+sul
        rv = __int_as_float(r.x);
        s1 = (myidx > 0) ? r.y : NATOMS;
        s2 = (myidx > 0) ? r.z : NATOMS;
    } else {
        rv = rij[p];
        s1 = (myidx > 0) ? su[p] : NATOMS;
        s2 = (myidx > 0) ? sul[p] : NATOMS;
    }
    if (srcs) {
        srcs[(size_t)gidja * 32 + n] = s1;
        srcs[(size_t)gidja * 32 + 16 + n] = s2;
    }
    if (hbf && blockIdx.x == 0 && threadIdx.x < HID)
        hbf[(size_t)NATOMS * HID + threadIdx.x] = 0;

    // two cooperative edge-row sweeps (one per atom), independent loads
    {
        int m = j >> 1, half = (j & 1) * 4;
        int p0 = __shfl(p, m, 32);          // lane m holds atom0 slot m
        int p1 = __shfl(p, 16 + m, 32);     // lane 16+m holds atom1 slot m
        float4 v0 = *(const float4*)&fdg[(size_t)p0 * FEAT + half];
        float4 v1 = *(const float4*)&fdg[(size_t)p1 * FEAT + half];
        *(float4*)&lbuf[grp][0][m][half] = v0;
        *(float4*)&lbuf[grp][1][m][half] = v1;
    }
    lbuf[grp][ja][n][8] = rv;
    lbuf[grp][ja][n][9] = valid;

    float wib[9];
#pragma unroll
    for (int k = 0; k < 9; k++) wib[k] = Wib[k * HID + j];

    __syncthreads();   // all 256 threads always reach

    float aggE[2];
#pragma unroll
    for (int a = 0; a < 2; a++) {
        float e = 0.f;
#pragma unroll
        for (int nn = 0; nn < MAXNEI; nn++) {
            const float* row = lbuf[grp][a][nn];
            float acc = row[8] * wib[8];
#pragma unroll
            for (int k = 0; k < FEAT; k++) acc = fmaf(row[k], wib[k], acc);
            e += row[9] * fmaxf(acc, 0.f);
        }
        aggE[a] = e;
    }

    float hj0 = 0.f, hj1 = 0.f;
#pragma unroll
    for (int k = 0; k < FEAT; k++) {
        hj0 = fmaf(tf[(size_t)gid0 * FEAT + k], Wia[k * HID + j], hj0);
        hj1 = fmaf(tf[(size_t)(gid0 + 1) * FEAT + k], Wia[k * HID + j], hj1);
    }

    float o0 = 0.f, o1 = 0.f;
#pragma unroll
    for (int k = 0; k < HID; k++) {
        float wv = Wh[k * HID + j];
        o0 = fmaf(__shfl(aggE[0], k, 32), wv, o0);
        o1 = fmaf(__shfl(aggE[1], k, 32), wv, o1);
    }
    h[(size_t)gid0 * HID + j] = hj0;
    h[(size_t)(gid0 + 1) * HID + j] = hj1;
    agg[(size_t)gid0 * HID + j] = o0;
    agg[(size_t)(gid0 + 1) * HID + j] = o1;
}

// GRU update, one thread per atom; xh in LDS (runtime-k broadcast reads);
// weights wave-uniform -> scalar loads. Writes fp32 h and optional bf16 mirror.
__global__ __launch_bounds__(GBLK) void k_gru(
        float* __restrict__ h, ushort_t* __restrict__ hbf,
        const float* __restrict__ agg,
        const float* __restrict__ Wz, const float* __restrict__ Wr,
        const float* __restrict__ Whh, const float* __restrict__ bz,
        const float* __restrict__ br, const float* __restrict__ bh) {
    __shared__ float xh[GBLK][65];
    int tid = threadIdx.x;
    int a = blockIdx.x * GBLK + tid;
    if (a >= NATOMS) return;   // no __syncthreads below
    float* myxh = xh[tid];

    float hreg[HID];
#pragma unroll
    for (int k = 0; k < HID; k += 4) {
        float4 av = *(const float4*)&agg[(size_t)a * HID + k];
        myxh[k] = av.x; myxh[k + 1] = av.y; myxh[k + 2] = av.z; myxh[k + 3] = av.w;
        float4 hv = *(const float4*)&h[(size_t)a * HID + k];
        hreg[k] = hv.x; hreg[k + 1] = hv.y; hreg[k + 2] = hv.z; hreg[k + 3] = hv.w;
        myxh[32 + k] = hv.x; myxh[33 + k] = hv.y; myxh[34 + k] = hv.z; myxh[35 + k] = hv.w;
    }

    float z[HID];
    {   // z pass
        float acc[HID];
#pragma unroll
        for (int jj = 0; jj < HID; jj++) acc[jj] = bz[jj];
        for (int k = 0; k < 2 * HID; k++) {
            float xk = myxh[k];
#pragma unroll
            for (int jj = 0; jj < HID; jj++) acc[jj] = fmaf(xk, Wz[k * HID + jj], acc[jj]);
        }
#pragma unroll
        for (int jj = 0; jj < HID; jj++) z[jj] = sigmoidf_(acc[jj]);
    }
    {   // r pass -> overwrite xh[32..63] with r*h
        float acc[HID];
#pragma unroll
        for (int jj = 0; jj < HID; jj++) acc[jj] = br[jj];
        for (int k = 0; k < 2 * HID; k++) {
            float xk = myxh[k];
#pragma unroll
            for (int jj = 0; jj < HID; jj++) acc[jj] = fmaf(xk, Wr[k * HID + jj], acc[jj]);
        }
#pragma unroll
        for (int jj = 0; jj < HID; jj++) myxh[32 + jj] = sigmoidf_(acc[jj]) * hreg[jj];
    }
    float o[HID];
    {   // candidate pass
        float acc[HID];
#pragma unroll
        for (int jj = 0; jj < HID; jj++) acc[jj] = bh[jj];
        for (int k = 0; k < 2 * HID; k++) {
            float xk = myxh[k];
#pragma unroll
            for (int jj = 0; jj < HID; jj++) acc[jj] = fmaf(xk, Whh[k * HID + jj], acc[jj]);
        }
#pragma unroll
        for (int jj = 0; jj < HID; jj++)
            o[jj] = (1.f - z[jj]) * hreg[jj] + z[jj] * tanhfast_(acc[jj]);
    }

#pragma unroll
    for (int jj = 0; jj < HID; jj += 4)
        *(float4*)&h[(size_t)a * HID + jj] = make_float4(o[jj], o[jj + 1], o[jj + 2], o[jj + 3]);

    if (hbf) {
        uint_t us[16];
#pragma unroll
        for (int jj = 0; jj < HID; jj += 2)
            us[jj >> 1] = (uint_t)f2bf(o[jj]) | ((uint_t)f2bf(o[jj + 1]) << 16);
        uint4* dst = (uint4*)(hbf + (size_t)a * HID);
#pragma unroll
        for (int q = 0; q < 4; q++)
            dst[q] = make_uint4(us[4 * q], us[4 * q + 1], us[4 * q + 2], us[4 * q + 3]);
    }
}

// agg = (sum of 32 gathered bf16 h rows) @ Wh. 2 atoms per 32-lane group;
// maskless via srcs table (invalid -> zero row NATOMS). 8 loads in flight/lane.
__global__ __launch_bounds__(256) void k_agg(
        const ushort_t* __restrict__ hbf, const int* __restrict__ srcs,
        const float* __restrict__ Wh, float* __restrict__ agg) {
    int grp = threadIdx.x >> 5;
    int j = threadIdx.x & 31;
    int gid0 = (blockIdx.x * 8 + grp) * 2;

    int s0 = srcs[(size_t)gid0 * 32 + j];
    int s1 = srcs[(size_t)(gid0 + 1) * 32 + j];

    int rslot = j >> 2;   // 0..7
    int c = j & 3;        // 16B quad within 64B row

    uint4 v0[4], v1[4];
#pragma unroll
    for (int s = 0; s < 4; s++) {
        int rs = s * 8 + rslot;
        int r0 = __shfl(s0, rs, 32);
        int r1 = __shfl(s1, rs, 32);
        v0[s] = ((const uint4*)(hbf + (size_t)r0 * HID))[c];
        v1[s] = ((const uint4*)(hbf + (size_t)r1 * HID))[c];
    }

    float acc0[8], acc1[8];
#pragma unroll
    for (int e = 0; e < 8; e++) { acc0[e] = 0.f; acc1[e] = 0.f; }
#pragma unroll
    for (int s = 0; s < 4; s++) {
        const uint_t* u0 = (const uint_t*)&v0[s];
        const uint_t* u1 = (const uint_t*)&v1[s];
#pragma unroll
        for (int e = 0; e < 8; e++) {
            uint_t w0 = u0[e >> 1], w1 = u1[e >> 1];
            acc0[e] += __uint_as_float((e & 1) ? (w0 & 0xffff0000u) : (w0 << 16));
            acc1[e] += __uint_as_float((e & 1) ? (w1 & 0xffff0000u) : (w1 << 16));
        }
    }
#pragma unroll
    for (int m = 4; m <= 16; m <<= 1) {
#pragma unroll
        for (int e = 0; e < 8; e++) {
            acc0[e] += __shfl_xor(acc0[e], m, 32);
            acc1[e] += __shfl_xor(acc1[e], m, 32);
        }
    }
    float o0 = 0.f, o1 = 0.f;
#pragma unroll
    for (int k = 0; k < HID; k++) {
        float a0k = __shfl(acc0[k & 7], k >> 3, 32);
        float a1k = __shfl(acc1[k & 7], k >> 3, 32);
        float wv = Wh[k * HID + j];
        o0 = fmaf(a0k, wv, o0);
        o1 = fmaf(a1k, wv, o1);
    }
    agg[(size_t)gid0 * HID + j] = o0;
    agg[(size_t)(gid0 + 1) * HID + j] = o1;
}

// fallback (ws too small): fp32 masked gather version
__global__ __launch_bounds__(256) void k_agg_fb(
        const float* __restrict__ hin, const int* __restrict__ bsc,
        const int* __restrict__ su, const int* __restrict__ sul,
        const float* __restrict__ Wh, float* __restrict__ agg) {
    int grp = threadIdx.x >> 5;
    int j = threadIdx.x & 31;
    int gid = blockIdx.x * 8 + grp;

    int myidx = (j < MAXNEI) ? bsc[gid * MAXNEI + j] : 0;
    size_t p = (myidx > 0) ? (size_t)(myidx - 1) : 0;
    int a1 = su[p];
    int a2 = sul[p];
    float valid = (myidx > 0) ? 1.f : 0.f;

    int rsel = (j >> 3) & 3;
    int c = j & 7;
    float4 acc = make_float4(0.f, 0.f, 0.f, 0.f);
#pragma unroll
    for (int s = 0; s < 8; s++) {
        int src = (4 * s + rsel) & 15;
        int row = __shfl((s < 4) ? a1 : a2, src, 32);
        float m = __shfl(valid, src, 32);
        float4 v = *(const float4*)&hin[(size_t)row * HID + c * 4];
        acc.x = fmaf(m, v.x, acc.x); acc.y = fmaf(m, v.y, acc.y);
        acc.z = fmaf(m, v.z, acc.z); acc.w = fmaf(m, v.w, acc.w);
    }
#pragma unroll
    for (int mlane = 8; mlane <= 16; mlane <<= 1) {
        acc.x += __shfl_xor(acc.x, mlane, 32);
        acc.y += __shfl_xor(acc.y, mlane, 32);
        acc.z += __shfl_xor(acc.z, mlane, 32);
        acc.w += __shfl_xor(acc.w, mlane, 32);
    }
    float out = 0.f;
#pragma unroll
    for (int k = 0; k < HID; k++) {
        float comp = ((k & 3) == 0) ? acc.x : ((k & 3) == 1) ? acc.y
                   : ((k & 3) == 2) ? acc.z : acc.w;
        float aggk = __shfl(comp, k >> 2, 32);
        out = fmaf(aggk, Wh[k * HID + j], out);
    }
    agg[(size_t)gid * HID + j] = out;
}

__global__ __launch_bounds__(256) void k_mol(
        const float* __restrict__ h, const int* __restrict__ lsc,
        float* __restrict__ out) {
    int m = blockIdx.x;
    int g = threadIdx.x >> 5;
    int j = threadIdx.x & 31;
    float acc = 0.f;
    for (int i = g; i < MAXATOMS; i += 8) {
        int idx = lsc[m * MAXATOMS + i];
        if (idx > 0) acc += h[(size_t)(idx - 1) * HID + j];
    }
    __shared__ float red[8][33];
    red[g][j] = acc;
    __syncthreads();
    if (g == 0) {
        float s = red[0][j] + red[1][j] + red[2][j] + red[3][j]
                + red[4][j] + red[5][j] + red[6][j] + red[7][j];
        out[m * HID + j] = s;
    }
}

extern "C" void kernel_launch(void* const* d_in, const int* in_sizes, int n_in,
                              void* d_out, int out_size, void* d_ws, size_t ws_size,
                              hipStream_t stream) {
    (void)in_sizes; (void)n_in; (void)out_size;
    const float* tf  = (const float*)d_in[0];
    const float* fdg = (const float*)d_in[1];
    const float* rij = (const float*)d_in[2];
    const int*   bsc = (const int*)d_in[3];
    const int*   lsc = (const int*)d_in[4];
    const int*   su  = (const int*)d_in[5];
    const int*   sul = (const int*)d_in[6];
    const float* Wia = (const float*)d_in[7];
    const float* Wib = (const float*)d_in[8];
    const float* Wh  = (const float*)d_in[9];
    const float* gWz = (const float*)d_in[10];
    const float* gWr = (const float*)d_in[11];
    const float* gWh = (const float*)d_in[12];
    const float* gbz = (const float*)d_in[13];
    const float* gbr = (const float*)d_in[14];
    const float* gbh = (const float*)d_in[15];
    float* out = (float*)d_out;

    char* ws = (char*)d_ws;
    const size_t HBYTES = (size_t)NATOMS * HID * 4;                 // 32 MB
    const size_t HBFBYTES = ((size_t)(NATOMS + 1) * HID * 2 + 255) & ~(size_t)255;
    const size_t SRCSBYTES = (size_t)NATOMS * 32 * 4;               // 32 MB
    const size_t RECBYTES = (size_t)NPAIRS * 16;                    // 64 MB
    float* h   = (float*)ws;                                        // 32 MB
    float* agg = (float*)(ws + HBYTES);                             // 32 MB
    ushort_t* hbf = (ushort_t*)(ws + 2 * HBYTES);                   // ~16 MB
    int* srcs = (int*)(ws + 2 * HBYTES + HBFBYTES);                 // 32 MB
    int4* rec = (int4*)(ws + 2 * HBYTES + HBFBYTES + SRCSBYTES);    // 64 MB
    const size_t NEED1 = 2 * HBYTES + HBFBYTES + SRCSBYTES;
    const size_t NEED2 = NEED1 + RECBYTES;
    bool fast = (ws_size >= NEED1);
    bool userec = (ws_size >= NEED2);
    if (!fast) { hbf = nullptr; srcs = nullptr; }
    if (!userec) { rec = nullptr; }

    dim3 igrid(NATOMS / 16);   // 15625, exact
    dim3 agrid(NATOMS / 8);    // for fallback k_agg_fb

    if (userec)
        k_prep<<<NPAIRS / 256, 256, 0, stream>>>(rij, su, sul, rec);

    k_init<<<igrid, 256, 0, stream>>>(tf, fdg, rij, bsc, su, sul, rec,
                                      Wia, Wib, Wh, h, agg, srcs, hbf);
    for (int d = 0; d < 3; d++) {
        ushort_t* hbf_w = (fast && d < 2) ? hbf : nullptr;
        k_gru<<<(NATOMS + GBLK - 1) / GBLK, GBLK, 0, stream>>>(
            h, hbf_w, agg, gWz + d * 2 * HID * HID, gWr + d * 2 * HID * HID,
            gWh + d * 2 * HID * HID, gbz + d * HID, gbr + d * HID, gbh + d * HID);
        if (d < 2) {
            if (fast)
                k_agg<<<igrid, 256, 0, stream>>>(hbf, srcs, Wh, agg);
            else
                k_agg_fb<<<agrid, 256, 0, stream>>>(h, bsc, su, sul, Wh, agg);
        }
    }
    k_mol<<<NMOL, 256, 0, stream>>>(h, lsc, out);
}

// Round 6
// 679.093 us; speedup vs baseline: 2.7875x; 1.0417x over previous
//
#include <hip/hip_runtime.h>

#define HID 32
#define NATOMS 250000
#define NPAIRS 4000000
#define MAXNEI 16
#define NMOL 2000
#define MAXATOMS 128
#define FEAT 8
#define GBLK 128

typedef unsigned short ushort_t;
typedef unsigned int uint_t;

__device__ __forceinline__ float sigmoidf_(float x) { return 1.f / (1.f + __expf(-x)); }
__device__ __forceinline__ float tanhfast_(float x) {
    float e = __expf(2.f * x);
    return 1.f - 2.f / (e + 1.f);
}
__device__ __forceinline__ ushort_t f2bf(float f) {   // RNE
    uint_t u = __float_as_uint(f);
    u = (u + 0x7fffu + ((u >> 16) & 1u)) >> 16;
    return (ushort_t)u;
}
__device__ __forceinline__ float bflo(uint_t w) { return __uint_as_float(w << 16); }
__device__ __forceinline__ float bfhi(uint_t w) { return __uint_as_float(w & 0xffff0000u); }

// ---------- Tier 3: 32B packed record {8xbf16 feats, f32 rij, su, sul, pad} ----------
__global__ __launch_bounds__(256) void k_prep32(
        const float* __restrict__ fdg, const float* __restrict__ rij,
        const int* __restrict__ su, const int* __restrict__ sul,
        uint4* __restrict__ rec) {
    int p = blockIdx.x * 256 + threadIdx.x;   // grid NPAIRS/256 exact
    const float4* f4 = (const float4*)(fdg + (size_t)p * FEAT);
    float4 a = f4[0], b = f4[1];
    uint4 lo;
    lo.x = (uint_t)f2bf(a.x) | ((uint_t)f2bf(a.y) << 16);
    lo.y = (uint_t)f2bf(a.z) | ((uint_t)f2bf(a.w) << 16);
    lo.z = (uint_t)f2bf(b.x) | ((uint_t)f2bf(b.y) << 16);
    lo.w = (uint_t)f2bf(b.z) | ((uint_t)f2bf(b.w) << 16);
    uint4 hi = make_uint4(__float_as_uint(rij[p]), (uint_t)su[p], (uint_t)sul[p], 0u);
    rec[(size_t)p * 2] = lo;
    rec[(size_t)p * 2 + 1] = hi;
}

// h0 = tf@Wia ; agg0 = (sum relu(edge@Wib))@Wh from 32B records; builds srcs.
// 2 atoms per 32-lane group, 8 groups/block, grid 15625 exact.
__global__ __launch_bounds__(256) void k_init_rec(
        const float* __restrict__ tf, const int* __restrict__ bsc,
        const uint4* __restrict__ rec,
        const float* __restrict__ Wia, const float* __restrict__ Wib,
        const float* __restrict__ Wh,
        float* __restrict__ h, float* __restrict__ agg,
        int* __restrict__ srcs, ushort_t* __restrict__ hbf) {
    __shared__ float lbuf[8][2][MAXNEI][12];  // [grp][atom][nei][f0..7, rij, valid, pad]
    int grp = threadIdx.x >> 5;
    int j = threadIdx.x & 31;
    int ja = j >> 4;
    int n = j & 15;
    int gid0 = (blockIdx.x * 8 + grp) * 2;
    int gidja = gid0 + ja;

    int myidx = bsc[gidja * MAXNEI + n];
    int p = (myidx > 0) ? (myidx - 1) : 0;
    float valid = (myidx > 0) ? 1.f : 0.f;

    uint4 lo = rec[(size_t)p * 2];        // independent loads, one 64B line
    uint4 hi = rec[(size_t)p * 2 + 1];

    srcs[(size_t)gidja * 32 + n]      = (myidx > 0) ? (int)hi.y : NATOMS;
    srcs[(size_t)gidja * 32 + 16 + n] = (myidx > 0) ? (int)hi.z : NATOMS;
    if (blockIdx.x == 0 && threadIdx.x < HID)
        hbf[(size_t)NATOMS * HID + threadIdx.x] = 0;

    float* row = lbuf[grp][ja][n];
    row[0] = bflo(lo.x); row[1] = bfhi(lo.x);
    row[2] = bflo(lo.y); row[3] = bfhi(lo.y);
    row[4] = bflo(lo.z); row[5] = bfhi(lo.z);
    row[6] = bflo(lo.w); row[7] = bfhi(lo.w);
    row[8] = __uint_as_float(hi.x);
    row[9] = valid;

    float wib[9];
#pragma unroll
    for (int k = 0; k < 9; k++) wib[k] = Wib[k * HID + j];

    float hj0 = 0.f, hj1 = 0.f;
#pragma unroll
    for (int k = 0; k < FEAT; k++) {
        hj0 = fmaf(tf[(size_t)gid0 * FEAT + k], Wia[k * HID + j], hj0);
        hj1 = fmaf(tf[(size_t)(gid0 + 1) * FEAT + k], Wia[k * HID + j], hj1);
    }

    __syncthreads();   // all 256 threads always reach

    float aggE[2];
#pragma unroll
    for (int a = 0; a < 2; a++) {
        float e = 0.f;
#pragma unroll
        for (int nn = 0; nn < MAXNEI; nn++) {
            const float* r = lbuf[grp][a][nn];
            float acc = r[8] * wib[8];
#pragma unroll
            for (int k = 0; k < FEAT; k++) acc = fmaf(r[k], wib[k], acc);
            e += r[9] * fmaxf(acc, 0.f);
        }
        aggE[a] = e;
    }

    float o0 = 0.f, o1 = 0.f;
#pragma unroll
    for (int k = 0; k < HID; k++) {
        float wv = Wh[k * HID + j];
        o0 = fmaf(__shfl(aggE[0], k, 32), wv, o0);
        o1 = fmaf(__shfl(aggE[1], k, 32), wv, o1);
    }
    h[(size_t)gid0 * HID + j] = hj0;
    h[(size_t)(gid0 + 1) * HID + j] = hj1;
    agg[(size_t)gid0 * HID + j] = o0;
    agg[(size_t)(gid0 + 1) * HID + j] = o1;
}

// agg = (sum of 32 gathered bf16 h rows) @ Wh. 4 atoms per 32-lane group,
// 4 groups per 128-thread block, grid 15625 exact. 16 loads in flight/lane.
__global__ __launch_bounds__(128) void k_agg4(
        const ushort_t* __restrict__ hbf, const int* __restrict__ srcs,
        const float* __restrict__ Wh, float* __restrict__ agg) {
    int grp = threadIdx.x >> 5;
    int j = threadIdx.x & 31;
    int gid0 = (blockIdx.x * 4 + grp) * 4;

    int s[4];
#pragma unroll
    for (int a = 0; a < 4; a++) s[a] = srcs[(size_t)(gid0 + a) * 32 + j];

    int rslot = j >> 2;   // 0..7
    int c = j & 3;        // 16B quad within 64B row

    uint4 v[4][4];
#pragma unroll
    for (int a = 0; a < 4; a++)
#pragma unroll
        for (int sw = 0; sw < 4; sw++) {
            int r = __shfl(s[a], sw * 8 + rslot, 32);
            v[a][sw] = ((const uint4*)(hbf + (size_t)r * HID))[c];
        }

    float acc[4][8];
#pragma unroll
    for (int a = 0; a < 4; a++)
#pragma unroll
        for (int e = 0; e < 8; e++) acc[a][e] = 0.f;
#pragma unroll
    for (int a = 0; a < 4; a++)
#pragma unroll
        for (int sw = 0; sw < 4; sw++) {
            const uint_t* u = (const uint_t*)&v[a][sw];
#pragma unroll
            for (int e = 0; e < 8; e++)
                acc[a][e] += (e & 1) ? bfhi(u[e >> 1]) : bflo(u[e >> 1]);
        }
#pragma unroll
    for (int m = 4; m <= 16; m <<= 1)
#pragma unroll
        for (int a = 0; a < 4; a++)
#pragma unroll
            for (int e = 0; e < 8; e++) acc[a][e] += __shfl_xor(acc[a][e], m, 32);

    float o[4] = {0.f, 0.f, 0.f, 0.f};
#pragma unroll
    for (int k = 0; k < HID; k++) {
        float wv = Wh[k * HID + j];
#pragma unroll
        for (int a = 0; a < 4; a++)
            o[a] = fmaf(__shfl(acc[a][k & 7], k >> 3, 32), wv, o[a]);
    }
#pragma unroll
    for (int a = 0; a < 4; a++) agg[(size_t)(gid0 + a) * HID + j] = o[a];
}

// ---------- Legacy tiers (smaller ws) ----------
__global__ __launch_bounds__(256) void k_prep16(
        const float* __restrict__ rij, const int* __restrict__ su,
        const int* __restrict__ sul, int4* __restrict__ rec) {
    int p = blockIdx.x * 256 + threadIdx.x;
    rec[p] = make_int4(__float_as_int(rij[p]), su[p], sul[p], 0);
}

__global__ __launch_bounds__(256) void k_init_legacy(
        const float* __restrict__ tf, const float* __restrict__ fdg,
        const float* __restrict__ rij, const int* __restrict__ bsc,
        const int* __restrict__ su, const int* __restrict__ sul,
        const int4* __restrict__ rec,
        const float* __restrict__ Wia, const float* __restrict__ Wib,
        const float* __restrict__ Wh,
        float* __restrict__ h, float* __restrict__ agg,
        int* __restrict__ srcs, ushort_t* __restrict__ hbf) {
    __shared__ float lbuf[8][2][MAXNEI][12];
    int grp = threadIdx.x >> 5;
    int j = threadIdx.x & 31;
    int ja = j >> 4;
    int n = j & 15;
    int gid0 = (blockIdx.x * 8 + grp) * 2;
    int gidja = gid0 + ja;

    int myidx = bsc[gidja * MAXNEI + n];
    int p = (myidx > 0) ? (myidx - 1) : 0;
    float valid = (myidx > 0) ? 1.f : 0.f;

    float rv;
    int s1, s2;
    if (rec) {
        int4 r = rec[p];
        rv = __int_as_float(r.x);
        s1 = (myidx > 0) ? r.y : NATOMS;
        s2 = (myidx > 0) ? r.z : NATOMS;
    } else {
        rv = rij[p];
        s1 = (myidx > 0) ? su[p] : NATOMS;
        s2 = (myidx > 0) ? sul[p] : NATOMS;
    }
    if (srcs) {
        srcs[(size_t)gidja * 32 + n] = s1;
        srcs[(size_t)gidja * 32 + 16 + n] = s2;
    }
    if (hbf && blockIdx.x == 0 && threadIdx.x < HID)
        hbf[(size_t)NATOMS * HID + threadIdx.x] = 0;

    {
        int m = j >> 1, half = (j & 1) * 4;
        int p0 = __shfl(p, m, 32);
        int p1 = __shfl(p, 16 + m, 32);
        float4 v0 = *(const float4*)&fdg[(size_t)p0 * FEAT + half];
        float4 v1 = *(const float4*)&fdg[(size_t)p1 * FEAT + half];
        *(float4*)&lbuf[grp][0][m][half] = v0;
        *(float4*)&lbuf[grp][1][m][half] = v1;
    }
    lbuf[grp][ja][n][8] = rv;
    lbuf[grp][ja][n][9] = valid;

    float wib[9];
#pragma unroll
    for (int k = 0; k < 9; k++) wib[k] = Wib[k * HID + j];

    __syncthreads();

    float aggE[2];
#pragma unroll
    for (int a = 0; a < 2; a++) {
        float e = 0.f;
#pragma unroll
        for (int nn = 0; nn < MAXNEI; nn++) {
            const float* row = lbuf[grp][a][nn];
            float acc = row[8] * wib[8];
#pragma unroll
            for (int k = 0; k < FEAT; k++) acc = fmaf(row[k], wib[k], acc);
            e += row[9] * fmaxf(acc, 0.f);
        }
        aggE[a] = e;
    }

    float hj0 = 0.f, hj1 = 0.f;
#pragma unroll
    for (int k = 0; k < FEAT; k++) {
        hj0 = fmaf(tf[(size_t)gid0 * FEAT + k], Wia[k * HID + j], hj0);
        hj1 = fmaf(tf[(size_t)(gid0 + 1) * FEAT + k], Wia[k * HID + j], hj1);
    }

    float o0 = 0.f, o1 = 0.f;
#pragma unroll
    for (int k = 0; k < HID; k++) {
        float wv = Wh[k * HID + j];
        o0 = fmaf(__shfl(aggE[0], k, 32), wv, o0);
        o1 = fmaf(__shfl(aggE[1], k, 32), wv, o1);
    }
    h[(size_t)gid0 * HID + j] = hj0;
    h[(size_t)(gid0 + 1) * HID + j] = hj1;
    agg[(size_t)gid0 * HID + j] = o0;
    agg[(size_t)(gid0 + 1) * HID + j] = o1;
}

__global__ __launch_bounds__(256) void k_agg2(
        const ushort_t* __restrict__ hbf, const int* __restrict__ srcs,
        const float* __restrict__ Wh, float* __restrict__ agg) {
    int grp = threadIdx.x >> 5;
    int j = threadIdx.x & 31;
    int gid0 = (blockIdx.x * 8 + grp) * 2;

    int s0 = srcs[(size_t)gid0 * 32 + j];
    int s1 = srcs[(size_t)(gid0 + 1) * 32 + j];
    int rslot = j >> 2;
    int c = j & 3;

    uint4 v0[4], v1[4];
#pragma unroll
    for (int s = 0; s < 4; s++) {
        int rs = s * 8 + rslot;
        int r0 = __shfl(s0, rs, 32);
        int r1 = __shfl(s1, rs, 32);
        v0[s] = ((const uint4*)(hbf + (size_t)r0 * HID))[c];
        v1[s] = ((const uint4*)(hbf + (size_t)r1 * HID))[c];
    }
    float acc0[8], acc1[8];
#pragma unroll
    for (int e = 0; e < 8; e++) { acc0[e] = 0.f; acc1[e] = 0.f; }
#pragma unroll
    for (int s = 0; s < 4; s++) {
        const uint_t* u0 = (const uint_t*)&v0[s];
        const uint_t* u1 = (const uint_t*)&v1[s];
#pragma unroll
        for (int e = 0; e < 8; e++) {
            acc0[e] += (e & 1) ? bfhi(u0[e >> 1]) : bflo(u0[e >> 1]);
            acc1[e] += (e & 1) ? bfhi(u1[e >> 1]) : bflo(u1[e >> 1]);
        }
    }
#pragma unroll
    for (int m = 4; m <= 16; m <<= 1)
#pragma unroll
        for (int e = 0; e < 8; e++) {
            acc0[e] += __shfl_xor(acc0[e], m, 32);
            acc1[e] += __shfl_xor(acc1[e], m, 32);
        }
    float o0 = 0.f, o1 = 0.f;
#pragma unroll
    for (int k = 0; k < HID; k++) {
        float wv = Wh[k * HID + j];
        o0 = fmaf(__shfl(acc0[k & 7], k >> 3, 32), wv, o0);
        o1 = fmaf(__shfl(acc1[k & 7], k >> 3, 32), wv, o1);
    }
    agg[(size_t)gid0 * HID + j] = o0;
    agg[(size_t)(gid0 + 1) * HID + j] = o1;
}

__global__ __launch_bounds__(256) void k_agg_fb(
        const float* __restrict__ hin, const int* __restrict__ bsc,
        const int* __restrict__ su, const int* __restrict__ sul,
        const float* __restrict__ Wh, float* __restrict__ agg) {
    int grp = threadIdx.x >> 5;
    int j = threadIdx.x & 31;
    int gid = blockIdx.x * 8 + grp;

    int myidx = (j < MAXNEI) ? bsc[gid * MAXNEI + j] : 0;
    size_t p = (myidx > 0) ? (size_t)(myidx - 1) : 0;
    int a1 = su[p];
    int a2 = sul[p];
    float valid = (myidx > 0) ? 1.f : 0.f;

    int rsel = (j >> 3) & 3;
    int c = j & 7;
    float4 acc = make_float4(0.f, 0.f, 0.f, 0.f);
#pragma unroll
    for (int s = 0; s < 8; s++) {
        int src = (4 * s + rsel) & 15;
        int row = __shfl((s < 4) ? a1 : a2, src, 32);
        float m = __shfl(valid, src, 32);
        float4 v = *(const float4*)&hin[(size_t)row * HID + c * 4];
        acc.x = fmaf(m, v.x, acc.x); acc.y = fmaf(m, v.y, acc.y);
        acc.z = fmaf(m, v.z, acc.z); acc.w = fmaf(m, v.w, acc.w);
    }
#pragma unroll
    for (int mlane = 8; mlane <= 16; mlane <<= 1) {
        acc.x += __shfl_xor(acc.x, mlane, 32);
        acc.y += __shfl_xor(acc.y, mlane, 32);
        acc.z += __shfl_xor(acc.z, mlane, 32);
        acc.w += __shfl_xor(acc.w, mlane, 32);
    }
    float out = 0.f;
#pragma unroll
    for (int k = 0; k < HID; k++) {
        float comp = ((k & 3) == 0) ? acc.x : ((k & 3) == 1) ? acc.y
                   : ((k & 3) == 2) ? acc.z : acc.w;
        out = fmaf(__shfl(comp, k >> 2, 32), Wh[k * HID + j], out);
    }
    agg[(size_t)gid * HID + j] = out;
}

// GRU update, one thread per atom; xh in LDS; weights wave-uniform.
__global__ __launch_bounds__(GBLK) void k_gru(
        float* __restrict__ h, ushort_t* __restrict__ hbf,
        const float* __restrict__ agg,
        const float* __restrict__ Wz, const float* __restrict__ Wr,
        const float* __restrict__ Whh, const float* __restrict__ bz,
        const float* __restrict__ br, const float* __restrict__ bh) {
    __shared__ float xh[GBLK][65];
    int tid = threadIdx.x;
    int a = blockIdx.x * GBLK + tid;
    if (a >= NATOMS) return;
    float* myxh = xh[tid];

    float hreg[HID];
#pragma unroll
    for (int k = 0; k < HID; k += 4) {
        float4 av = *(const float4*)&agg[(size_t)a * HID + k];
        myxh[k] = av.x; myxh[k + 1] = av.y; myxh[k + 2] = av.z; myxh[k + 3] = av.w;
        float4 hv = *(const float4*)&h[(size_t)a * HID + k];
        hreg[k] = hv.x; hreg[k + 1] = hv.y; hreg[k + 2] = hv.z; hreg[k + 3] = hv.w;
        myxh[32 + k] = hv.x; myxh[33 + k] = hv.y; myxh[34 + k] = hv.z; myxh[35 + k] = hv.w;
    }

    float z[HID];
    {
        float acc[HID];
#pragma unroll
        for (int jj = 0; jj < HID; jj++) acc[jj] = bz[jj];
        for (int k = 0; k < 2 * HID; k++) {
            float xk = myxh[k];
#pragma unroll
            for (int jj = 0; jj < HID; jj++) acc[jj] = fmaf(xk, Wz[k * HID + jj], acc[jj]);
        }
#pragma unroll
        for (int jj = 0; jj < HID; jj++) z[jj] = sigmoidf_(acc[jj]);
    }
    {
        float acc[HID];
#pragma unroll
        for (int jj = 0; jj < HID; jj++) acc[jj] = br[jj];
        for (int k = 0; k < 2 * HID; k++) {
            float xk = myxh[k];
#pragma unroll
            for (int jj = 0; jj < HID; jj++) acc[jj] = fmaf(xk, Wr[k * HID + jj], acc[jj]);
        }
#pragma unroll
        for (int jj = 0; jj < HID; jj++) myxh[32 + jj] = sigmoidf_(acc[jj]) * hreg[jj];
    }
    float o[HID];
    {
        float acc[HID];
#pragma unroll
        for (int jj = 0; jj < HID; jj++) acc[jj] = bh[jj];
        for (int k = 0; k < 2 * HID; k++) {
            float xk = myxh[k];
#pragma unroll
            for (int jj = 0; jj < HID; jj++) acc[jj] = fmaf(xk, Whh[k * HID + jj], acc[jj]);
        }
#pragma unroll
        for (int jj = 0; jj < HID; jj++)
            o[jj] = (1.f - z[jj]) * hreg[jj] + z[jj] * tanhfast_(acc[jj]);
    }

#pragma unroll
    for (int jj = 0; jj < HID; jj += 4)
        *(float4*)&h[(size_t)a * HID + jj] = make_float4(o[jj], o[jj + 1], o[jj + 2], o[jj + 3]);

    if (hbf) {
        uint_t us[16];
#pragma unroll
        for (int jj = 0; jj < HID; jj += 2)
            us[jj >> 1] = (uint_t)f2bf(o[jj]) | ((uint_t)f2bf(o[jj + 1]) << 16);
        uint4* dst = (uint4*)(hbf + (size_t)a * HID);
#pragma unroll
        for (int q = 0; q < 4; q++)
            dst[q] = make_uint4(us[4 * q], us[4 * q + 1], us[4 * q + 2], us[4 * q + 3]);
    }
}

__global__ __launch_bounds__(256) void k_mol(
        const float* __restrict__ h, const int* __restrict__ lsc,
        float* __restrict__ out) {
    int m = blockIdx.x;
    int g = threadIdx.x >> 5;
    int j = threadIdx.x & 31;
    float acc = 0.f;
    for (int i = g; i < MAXATOMS; i += 8) {
        int idx = lsc[m * MAXATOMS + i];
        if (idx > 0) acc += h[(size_t)(idx - 1) * HID + j];
    }
    __shared__ float red[8][33];
    red[g][j] = acc;
    __syncthreads();
    if (g == 0) {
        float s = red[0][j] + red[1][j] + red[2][j] + red[3][j]
                + red[4][j] + red[5][j] + red[6][j] + red[7][j];
        out[m * HID + j] = s;
    }
}

extern "C" void kernel_launch(void* const* d_in, const int* in_sizes, int n_in,
                              void* d_out, int out_size, void* d_ws, size_t ws_size,
                              hipStream_t stream) {
    (void)in_sizes; (void)n_in; (void)out_size;
    const float* tf  = (const float*)d_in[0];
    const float* fdg = (const float*)d_in[1];
    const float* rij = (const float*)d_in[2];
    const int*   bsc = (const int*)d_in[3];
    const int*   lsc = (const int*)d_in[4];
    const int*   su  = (const int*)d_in[5];
    const int*   sul = (const int*)d_in[6];
    const float* Wia = (const float*)d_in[7];
    const float* Wib = (const float*)d_in[8];
    const float* Wh  = (const float*)d_in[9];
    const float* gWz = (const float*)d_in[10];
    const float* gWr = (const float*)d_in[11];
    const float* gWh = (const float*)d_in[12];
    const float* gbz = (const float*)d_in[13];
    const float* gbr = (const float*)d_in[14];
    const float* gbh = (const float*)d_in[15];
    float* out = (float*)d_out;

    char* ws = (char*)d_ws;
    const size_t HBYTES = (size_t)NATOMS * HID * 4;                 // 32 MB
    const size_t HBFBYTES = ((size_t)(NATOMS + 1) * HID * 2 + 255) & ~(size_t)255;
    const size_t SRCSBYTES = (size_t)NATOMS * 32 * 4;               // 32 MB
    const size_t REC16B = (size_t)NPAIRS * 16;                      // 64 MB
    const size_t REC32B = (size_t)NPAIRS * 32;                      // 128 MB
    float* h   = (float*)ws;
    float* agg = (float*)(ws + HBYTES);
    ushort_t* hbf = (ushort_t*)(ws + 2 * HBYTES);
    int* srcs = (int*)(ws + 2 * HBYTES + HBFBYTES);
    char* recbase = ws + 2 * HBYTES + HBFBYTES + SRCSBYTES;
    const size_t NEED1 = 2 * HBYTES + HBFBYTES + SRCSBYTES;         // ~112 MB
    const size_t NEED2 = NEED1 + REC16B;                            // ~176 MB
    const size_t NEED3 = NEED1 + REC32B;                            // ~240 MB
    bool fast   = (ws_size >= NEED1);
    bool rec16  = (ws_size >= NEED2);
    bool rec32  = (ws_size >= NEED3);
    if (!fast) { hbf = nullptr; srcs = nullptr; }

    dim3 igrid(NATOMS / 16);    // 15625
    dim3 agrid4(NATOMS / 16);   // 15625 (k_agg4: 16 atoms/block)
    dim3 agrid2(NATOMS / 16);   // k_agg2: 16 atoms/block too
    dim3 afb(NATOMS / 8);

    if (rec32) {
        uint4* rec = (uint4*)recbase;
        k_prep32<<<NPAIRS / 256, 256, 0, stream>>>(fdg, rij, su, sul, rec);
        k_init_rec<<<igrid, 256, 0, stream>>>(tf, bsc, rec, Wia, Wib, Wh,
                                              h, agg, srcs, hbf);
    } else {
        int4* rec = rec16 ? (int4*)recbase : nullptr;
        if (rec16)
            k_prep16<<<NPAIRS / 256, 256, 0, stream>>>(rij, su, sul, rec);
        k_init_legacy<<<igrid, 256, 0, stream>>>(tf, fdg, rij, bsc, su, sul, rec,
                                                 Wia, Wib, Wh, h, agg, srcs, hbf);
    }

    for (int d = 0; d < 3; d++) {
        ushort_t* hbf_w = (fast && d < 2) ? hbf : nullptr;
        k_gru<<<(NATOMS + GBLK - 1) / GBLK, GBLK, 0, stream>>>(
            h, hbf_w, agg, gWz + d * 2 * HID * HID, gWr + d * 2 * HID * HID,
            gWh + d * 2 * HID * HID, gbz + d * HID, gbr + d * HID, gbh + d * HID);
        if (d < 2) {
            if (fast && rec32)
                k_agg4<<<agrid4, 128, 0, stream>>>(hbf, srcs, Wh, agg);
            else if (fast)
                k_agg2<<<agrid2, 256, 0, stream>>>(hbf, srcs, Wh, agg);
            else
                k_agg_fb<<<afb, 256, 0, stream>>>(h, bsc, su, sul, Wh, agg);
        }
    }
    k_mol<<<NMOL, 256, 0, stream>>>(h, lsc, out);
}

// Round 8
// 541.309 us; speedup vs baseline: 3.4970x; 1.2545x over previous
//
#include <hip/hip_runtime.h>

#define HID 32
#define NATOMS 250000
#define NPAIRS 4000000
#define MAXNEI 16
#define NMOL 2000
#define MAXATOMS 128
#define FEAT 8

typedef unsigned short ushort_t;
typedef unsigned int uint_t;
typedef short bf16x8 __attribute__((ext_vector_type(8)));
typedef float f32x4 __attribute__((ext_vector_type(4)));

__device__ __forceinline__ float sigmoidf_(float x) { return 1.f / (1.f + __expf(-x)); }
__device__ __forceinline__ float tanhfast_(float x) {
    float e = __expf(2.f * x);
    return 1.f - 2.f / (e + 1.f);
}
__device__ __forceinline__ ushort_t f2bf(float f) {   // RNE
    uint_t u = __float_as_uint(f);
    u = (u + 0x7fffu + ((u >> 16) & 1u)) >> 16;
    return (ushort_t)u;
}
__device__ __forceinline__ float bf2f(ushort_t h) { return __uint_as_float((uint_t)h << 16); }
__device__ __forceinline__ float bflo(uint_t w) { return __uint_as_float(w << 16); }
__device__ __forceinline__ float bfhi(uint_t w) { return __uint_as_float(w & 0xffff0000u); }
// split x into hi+lo bf16 pair (16 effective mantissa bits)
__device__ __forceinline__ void splitbf(float x, short& hi, short& lo) {
    ushort_t h = f2bf(x);
    hi = (short)h;
    lo = (short)f2bf(x - bf2f(h));
}

// ---------- prep: 32B packed record {8xbf16 feats, f32 rij, su, sul, pad} ----------
__global__ __launch_bounds__(256) void k_prep32(
        const float* __restrict__ fdg, const float* __restrict__ rij,
        const int* __restrict__ su, const int* __restrict__ sul,
        uint4* __restrict__ rec) {
    int p = blockIdx.x * 256 + threadIdx.x;   // grid NPAIRS/256 exact
    const float4* f4 = (const float4*)(fdg + (size_t)p * FEAT);
    float4 a = f4[0], b = f4[1];
    uint4 lo;
    lo.x = (uint_t)f2bf(a.x) | ((uint_t)f2bf(a.y) << 16);
    lo.y = (uint_t)f2bf(a.z) | ((uint_t)f2bf(a.w) << 16);
    lo.z = (uint_t)f2bf(b.x) | ((uint_t)f2bf(b.y) << 16);
    lo.w = (uint_t)f2bf(b.z) | ((uint_t)f2bf(b.w) << 16);
    uint4 hi = make_uint4(__float_as_uint(rij[p]), (uint_t)su[p], (uint_t)sul[p], 0u);
    rec[(size_t)p * 2] = lo;
    rec[(size_t)p * 2 + 1] = hi;
}

// h0 = tf@Wia ; agg0 = (sum relu(edge@Wib))@Wh from 32B records; builds srcs.
__global__ __launch_bounds__(256) void k_init_rec(
        const float* __restrict__ tf, const int* __restrict__ bsc,
        const uint4* __restrict__ rec,
        const float* __restrict__ Wia, const float* __restrict__ Wib,
        const float* __restrict__ Wh,
        float* __restrict__ h, float* __restrict__ agg,
        int* __restrict__ srcs, ushort_t* __restrict__ hbf) {
    __shared__ float lbuf[8][2][MAXNEI][12];
    int grp = threadIdx.x >> 5;
    int j = threadIdx.x & 31;
    int ja = j >> 4;
    int n = j & 15;
    int gid0 = (blockIdx.x * 8 + grp) * 2;
    int gidja = gid0 + ja;

    int myidx = bsc[gidja * MAXNEI + n];
    int p = (myidx > 0) ? (myidx - 1) : 0;
    float valid = (myidx > 0) ? 1.f : 0.f;

    uint4 lo = rec[(size_t)p * 2];
    uint4 hi = rec[(size_t)p * 2 + 1];

    srcs[(size_t)gidja * 32 + n]      = (myidx > 0) ? (int)hi.y : NATOMS;
    srcs[(size_t)gidja * 32 + 16 + n] = (myidx > 0) ? (int)hi.z : NATOMS;
    if (blockIdx.x == 0 && threadIdx.x < HID)
        hbf[(size_t)NATOMS * HID + threadIdx.x] = 0;

    float* row = lbuf[grp][ja][n];
    row[0] = bflo(lo.x); row[1] = bfhi(lo.x);
    row[2] = bflo(lo.y); row[3] = bfhi(lo.y);
    row[4] = bflo(lo.z); row[5] = bfhi(lo.z);
    row[6] = bflo(lo.w); row[7] = bfhi(lo.w);
    row[8] = __uint_as_float(hi.x);
    row[9] = valid;

    float wib[9];
#pragma unroll
    for (int k = 0; k < 9; k++) wib[k] = Wib[k * HID + j];

    float hj0 = 0.f, hj1 = 0.f;
#pragma unroll
    for (int k = 0; k < FEAT; k++) {
        hj0 = fmaf(tf[(size_t)gid0 * FEAT + k], Wia[k * HID + j], hj0);
        hj1 = fmaf(tf[(size_t)(gid0 + 1) * FEAT + k], Wia[k * HID + j], hj1);
    }

    __syncthreads();

    float aggE[2];
#pragma unroll
    for (int a = 0; a < 2; a++) {
        float e = 0.f;
#pragma unroll
        for (int nn = 0; nn < MAXNEI; nn++) {
            const float* r = lbuf[grp][a][nn];
            float acc = r[8] * wib[8];
#pragma unroll
            for (int k = 0; k < FEAT; k++) acc = fmaf(r[k], wib[k], acc);
            e += r[9] * fmaxf(acc, 0.f);
        }
        aggE[a] = e;
    }

    float o0 = 0.f, o1 = 0.f;
#pragma unroll
    for (int k = 0; k < HID; k++) {
        float wv = Wh[k * HID + j];
        o0 = fmaf(__shfl(aggE[0], k, 32), wv, o0);
        o1 = fmaf(__shfl(aggE[1], k, 32), wv, o1);
    }
    h[(size_t)gid0 * HID + j] = hj0;
    h[(size_t)(gid0 + 1) * HID + j] = hj1;
    agg[(size_t)gid0 * HID + j] = o0;
    agg[(size_t)(gid0 + 1) * HID + j] = o1;
}

// ---------- MFMA GRU, split-bf16 (hi+lo) for ~fp32 precision ----------
// A layout: lane l holds A[row=l&15][cols 8*(l>>4)..+7]
// B layout: lane l holds B[rows 8*(l>>4)..+7][col=l&15]
// C layout: lane l reg q -> row (l>>4)*4+q, col l&15   [m89-verified]
__global__ __launch_bounds__(256) void k_gru_mfma(
        float* __restrict__ h, ushort_t* __restrict__ hbf,
        const float* __restrict__ agg,
        const float* __restrict__ Wz, const float* __restrict__ Wr,
        const float* __restrict__ Whh, const float* __restrict__ bz,
        const float* __restrict__ br, const float* __restrict__ bh) {
    __shared__ float rhlds[4][16][36];   // fp32 r*h relayout; 9216 B/block
    int wid = threadIdx.x >> 6;
    int l = threadIdx.x & 63;
    int g = l >> 4;                // 0..3
    int cl = l & 15;               // 0..15
    int A0 = blockIdx.x * 64 + wid * 16;

    // --- A-frags (coalesced global), split hi/lo ---
    int rowA = min(A0 + cl, NATOMS - 1);
    const float4* ap = (const float4*)(agg + (size_t)rowA * HID + g * 8);
    float4 fa0 = ap[0], fa1 = ap[1];
    const float4* hp = (const float4*)(h + (size_t)rowA * HID + g * 8);
    float4 fh0 = hp[0], fh1 = hp[1];
    bf16x8 a0h, a0l, a1h, a1l;
    {
        const float* fa = (const float*)&fa0;   // fa0,fa1 contiguous? no — copy
        float av[8] = {fa0.x, fa0.y, fa0.z, fa0.w, fa1.x, fa1.y, fa1.z, fa1.w};
        float hv[8] = {fh0.x, fh0.y, fh0.z, fh0.w, fh1.x, fh1.y, fh1.z, fh1.w};
        (void)fa;
#pragma unroll
        for (int m = 0; m < 8; m++) {
            short th, tl;
            splitbf(av[m], th, tl); a0h[m] = th; a0l[m] = tl;
            splitbf(hv[m], th, tl); a1h[m] = th; a1l[m] = tl;
        }
    }

    // --- h in C layout (for r*h and the (1-z)h term) ---
    int rowC = A0 + g * 4;
    float hC[4][2];
#pragma unroll
    for (int q = 0; q < 4; q++) {
        int r = min(rowC + q, NATOMS - 1);
#pragma unroll
        for (int nt = 0; nt < 2; nt++)
            hC[q][nt] = h[(size_t)r * HID + nt * 16 + cl];
    }

    // --- B-frag loader with hi/lo split (weights L1-hot) ---
#define LOADB(W, kstep, nt, dh, dl) { \
        _Pragma("unroll") \
        for (int m = 0; m < 8; m++) { \
            float w = (W)[((kstep) * 32 + g * 8 + m) * HID + (nt) * 16 + cl]; \
            short th, tl; splitbf(w, th, tl); dh[m] = th; dl[m] = tl; } }
    // 3-product split matmul: ah@bh + ah@bl + al@bh  (~fp32 precision)
#define MM3(ah, al, bh, bl, acc) { \
        acc = __builtin_amdgcn_mfma_f32_16x16x32_bf16(ah, bh, acc, 0, 0, 0); \
        acc = __builtin_amdgcn_mfma_f32_16x16x32_bf16(ah, bl, acc, 0, 0, 0); \
        acc = __builtin_amdgcn_mfma_f32_16x16x32_bf16(al, bh, acc, 0, 0, 0); }

    f32x4 zacc[2], racc[2];
#pragma unroll
    for (int nt = 0; nt < 2; nt++) {
        bf16x8 b0h, b0l, b1h, b1l;
        LOADB(Wz, 0, nt, b0h, b0l); LOADB(Wz, 1, nt, b1h, b1l);
        f32x4 acc = {0.f, 0.f, 0.f, 0.f};
        MM3(a0h, a0l, b0h, b0l, acc);
        MM3(a1h, a1l, b1h, b1l, acc);
        zacc[nt] = acc;
        LOADB(Wr, 0, nt, b0h, b0l); LOADB(Wr, 1, nt, b1h, b1l);
        f32x4 acc2 = {0.f, 0.f, 0.f, 0.f};
        MM3(a0h, a0l, b0h, b0l, acc2);
        MM3(a1h, a1l, b1h, b1l, acc2);
        racc[nt] = acc2;
    }

    float z[4][2];
#pragma unroll
    for (int nt = 0; nt < 2; nt++) {
        float bzv = bz[nt * 16 + cl];
        float brv = br[nt * 16 + cl];
#pragma unroll
        for (int q = 0; q < 4; q++) {
            z[q][nt] = sigmoidf_(zacc[nt][q] + bzv);
            float rv = sigmoidf_(racc[nt][q] + brv);
            rhlds[wid][g * 4 + q][nt * 16 + cl] = rv * hC[q][nt];   // fp32
        }
    }

    // wave-local LDS RAW: wait our writes, block hoisting of the read
    asm volatile("s_waitcnt lgkmcnt(0)" ::: "memory");
    __builtin_amdgcn_sched_barrier(0);

    bf16x8 a2h, a2l;
    {
        float4 r0 = *(const float4*)&rhlds[wid][cl][g * 8];
        float4 r1 = *(const float4*)&rhlds[wid][cl][g * 8 + 4];
        float rv[8] = {r0.x, r0.y, r0.z, r0.w, r1.x, r1.y, r1.z, r1.w};
#pragma unroll
        for (int m = 0; m < 8; m++) {
            short th, tl;
            splitbf(rv[m], th, tl); a2h[m] = th; a2l[m] = tl;
        }
    }

    f32x4 hcacc[2];
#pragma unroll
    for (int nt = 0; nt < 2; nt++) {
        bf16x8 b0h, b0l, b1h, b1l;
        LOADB(Whh, 0, nt, b0h, b0l); LOADB(Whh, 1, nt, b1h, b1l);
        f32x4 acc = {0.f, 0.f, 0.f, 0.f};
        MM3(a0h, a0l, b0h, b0l, acc);
        MM3(a2h, a2l, b1h, b1l, acc);
        hcacc[nt] = acc;
    }
#undef LOADB
#undef MM3

#pragma unroll
    for (int nt = 0; nt < 2; nt++) {
        float bhv = bh[nt * 16 + cl];
#pragma unroll
        for (int q = 0; q < 4; q++) {
            int r = rowC + q;
            if (r < NATOMS) {
                float hc = tanhfast_(hcacc[nt][q] + bhv);
                float zz = z[q][nt];
                float hn = (1.f - zz) * hC[q][nt] + zz * hc;
                h[(size_t)r * HID + nt * 16 + cl] = hn;
                if (hbf) hbf[(size_t)r * HID + nt * 16 + cl] = f2bf(hn);
            }
        }
    }
}

// agg = (sum of 32 gathered bf16 h rows) @ Wh. 4 atoms per 32-lane group.
__global__ __launch_bounds__(128) void k_agg4(
        const ushort_t* __restrict__ hbf, const int* __restrict__ srcs,
        const float* __restrict__ Wh, float* __restrict__ agg) {
    int grp = threadIdx.x >> 5;
    int j = threadIdx.x & 31;
    int gid0 = (blockIdx.x * 4 + grp) * 4;

    int s[4];
#pragma unroll
    for (int a = 0; a < 4; a++) s[a] = srcs[(size_t)(gid0 + a) * 32 + j];

    int rslot = j >> 2;
    int c = j & 3;

    uint4 v[4][4];
#pragma unroll
    for (int a = 0; a < 4; a++)
#pragma unroll
        for (int sw = 0; sw < 4; sw++) {
            int r = __shfl(s[a], sw * 8 + rslot, 32);
            v[a][sw] = ((const uint4*)(hbf + (size_t)r * HID))[c];
        }

    float acc[4][8];
#pragma unroll
    for (int a = 0; a < 4; a++)
#pragma unroll
        for (int e = 0; e < 8; e++) acc[a][e] = 0.f;
#pragma unroll
    for (int a = 0; a < 4; a++)
#pragma unroll
        for (int sw = 0; sw < 4; sw++) {
            const uint_t* u = (const uint_t*)&v[a][sw];
#pragma unroll
            for (int e = 0; e < 8; e++)
                acc[a][e] += (e & 1) ? bfhi(u[e >> 1]) : bflo(u[e >> 1]);
        }
#pragma unroll
    for (int m = 4; m <= 16; m <<= 1)
#pragma unroll
        for (int a = 0; a < 4; a++)
#pragma unroll
            for (int e = 0; e < 8; e++) acc[a][e] += __shfl_xor(acc[a][e], m, 32);

    float o[4] = {0.f, 0.f, 0.f, 0.f};
#pragma unroll
    for (int k = 0; k < HID; k++) {
        float wv = Wh[k * HID + j];
#pragma unroll
        for (int a = 0; a < 4; a++)
            o[a] = fmaf(__shfl(acc[a][k & 7], k >> 3, 32), wv, o[a]);
    }
#pragma unroll
    for (int a = 0; a < 4; a++) agg[(size_t)(gid0 + a) * HID + j] = o[a];
}

// ---------- Legacy tiers (smaller ws) ----------
__global__ __launch_bounds__(256) void k_prep16(
        const float* __restrict__ rij, const int* __restrict__ su,
        const int* __restrict__ sul, int4* __restrict__ rec) {
    int p = blockIdx.x * 256 + threadIdx.x;
    rec[p] = make_int4(__float_as_int(rij[p]), su[p], sul[p], 0);
}

__global__ __launch_bounds__(256) void k_init_legacy(
        const float* __restrict__ tf, const float* __restrict__ fdg,
        const float* __restrict__ rij, const int* __restrict__ bsc,
        const int* __restrict__ su, const int* __restrict__ sul,
        const int4* __restrict__ rec,
        const float* __restrict__ Wia, const float* __restrict__ Wib,
        const float* __restrict__ Wh,
        float* __restrict__ h, float* __restrict__ agg,
        int* __restrict__ srcs, ushort_t* __restrict__ hbf) {
    __shared__ float lbuf[8][2][MAXNEI][12];
    int grp = threadIdx.x >> 5;
    int j = threadIdx.x & 31;
    int ja = j >> 4;
    int n = j & 15;
    int gid0 = (blockIdx.x * 8 + grp) * 2;
    int gidja = gid0 + ja;

    int myidx = bsc[gidja * MAXNEI + n];
    int p = (myidx > 0) ? (myidx - 1) : 0;
    float valid = (myidx > 0) ? 1.f : 0.f;

    float rv;
    int s1, s2;
    if (rec) {
        int4 r = rec[p];
        rv = __int_as_float(r.x);
        s1 = (myidx > 0) ? r.y : NATOMS;
        s2 = (myidx > 0) ? r.z : NATOMS;
    } else {
        rv = rij[p];
        s1 = (myidx > 0) ? su[p] : NATOMS;
        s2 = (myidx > 0) ? sul[p] : NATOMS;
    }
    if (srcs) {
        srcs[(size_t)gidja * 32 + n] = s1;
        srcs[(size_t)gidja * 32 + 16 + n] = s2;
    }
    if (hbf && blockIdx.x == 0 && threadIdx.x < HID)
        hbf[(size_t)NATOMS * HID + threadIdx.x] = 0;

    {
        int m = j >> 1, half = (j & 1) * 4;
        int p0 = __shfl(p, m, 32);
        int p1 = __shfl(p, 16 + m, 32);
        float4 v0 = *(const float4*)&fdg[(size_t)p0 * FEAT + half];
        float4 v1 = *(const float4*)&fdg[(size_t)p1 * FEAT + half];
        *(float4*)&lbuf[grp][0][m][half] = v0;
        *(float4*)&lbuf[grp][1][m][half] = v1;
    }
    lbuf[grp][ja][n][8] = rv;
    lbuf[grp][ja][n][9] = valid;

    float wib[9];
#pragma unroll
    for (int k = 0; k < 9; k++) wib[k] = Wib[k * HID + j];

    __syncthreads();

    float aggE[2];
#pragma unroll
    for (int a = 0; a < 2; a++) {
        float e = 0.f;
#pragma unroll
        for (int nn = 0; nn < MAXNEI; nn++) {
            const float* row = lbuf[grp][a][nn];
            float acc = row[8] * wib[8];
#pragma unroll
            for (int k = 0; k < FEAT; k++) acc = fmaf(row[k], wib[k], acc);
            e += row[9] * fmaxf(acc, 0.f);
        }
        aggE[a] = e;
    }

    float hj0 = 0.f, hj1 = 0.f;
#pragma unroll
    for (int k = 0; k < FEAT; k++) {
        hj0 = fmaf(tf[(size_t)gid0 * FEAT + k], Wia[k * HID + j], hj0);
        hj1 = fmaf(tf[(size_t)(gid0 + 1) * FEAT + k], Wia[k * HID + j], hj1);
    }

    float o0 = 0.f, o1 = 0.f;
#pragma unroll
    for (int k = 0; k < HID; k++) {
        float wv = Wh[k * HID + j];
        o0 = fmaf(__shfl(aggE[0], k, 32), wv, o0);
        o1 = fmaf(__shfl(aggE[1], k, 32), wv, o1);
    }
    h[(size_t)gid0 * HID + j] = hj0;
    h[(size_t)(gid0 + 1) * HID + j] = hj1;
    agg[(size_t)gid0 * HID + j] = o0;
    agg[(size_t)(gid0 + 1) * HID + j] = o1;
}

__global__ __launch_bounds__(256) void k_agg2(
        const ushort_t* __restrict__ hbf, const int* __restrict__ srcs,
        const float* __restrict__ Wh, float* __restrict__ agg) {
    int grp = threadIdx.x >> 5;
    int j = threadIdx.x & 31;
    int gid0 = (blockIdx.x * 8 + grp) * 2;

    int s0 = srcs[(size_t)gid0 * 32 + j];
    int s1 = srcs[(size_t)(gid0 + 1) * 32 + j];
    int rslot = j >> 2;
    int c = j & 3;

    uint4 v0[4], v1[4];
#pragma unroll
    for (int s = 0; s < 4; s++) {
        int rs = s * 8 + rslot;
        int r0 = __shfl(s0, rs, 32);
        int r1 = __shfl(s1, rs, 32);
        v0[s] = ((const uint4*)(hbf + (size_t)r0 * HID))[c];
        v1[s] = ((const uint4*)(hbf + (size_t)r1 * HID))[c];
    }
    float acc0[8], acc1[8];
#pragma unroll
    for (int e = 0; e < 8; e++) { acc0[e] = 0.f; acc1[e] = 0.f; }
#pragma unroll
    for (int s = 0; s < 4; s++) {
        const uint_t* u0 = (const uint_t*)&v0[s];
        const uint_t* u1 = (const uint_t*)&v1[s];
#pragma unroll
        for (int e = 0; e < 8; e++) {
            acc0[e] += (e & 1) ? bfhi(u0[e >> 1]) : bflo(u0[e >> 1]);
            acc1[e] += (e & 1) ? bfhi(u1[e >> 1]) : bflo(u1[e >> 1]);
        }
    }
#pragma unroll
    for (int m = 4; m <= 16; m <<= 1)
#pragma unroll
        for (int e = 0; e < 8; e++) {
            acc0[e] += __shfl_xor(acc0[e], m, 32);
            acc1[e] += __shfl_xor(acc1[e], m, 32);
        }
    float o0 = 0.f, o1 = 0.f;
#pragma unroll
    for (int k = 0; k < HID; k++) {
        float wv = Wh[k * HID + j];
        o0 = fmaf(__shfl(acc0[k & 7], k >> 3, 32), wv, o0);
        o1 = fmaf(__shfl(acc1[k & 7], k >> 3, 32), wv, o1);
    }
    agg[(size_t)gid0 * HID + j] = o0;
    agg[(size_t)(gid0 + 1) * HID + j] = o1;
}

__global__ __launch_bounds__(256) void k_agg_fb(
        const float* __restrict__ hin, const int* __restrict__ bsc,
        const int* __restrict__ su, const int* __restrict__ sul,
        const float* __restrict__ Wh, float* __restrict__ agg) {
    int grp = threadIdx.x >> 5;
    int j = threadIdx.x & 31;
    int gid = blockIdx.x * 8 + grp;

    int myidx = (j < MAXNEI) ? bsc[gid * MAXNEI + j] : 0;
    size_t p = (myidx > 0) ? (size_t)(myidx - 1) : 0;
    int a1 = su[p];
    int a2 = sul[p];
    float valid = (myidx > 0) ? 1.f : 0.f;

    int rsel = (j >> 3) & 3;
    int c = j & 7;
    float4 acc = make_float4(0.f, 0.f, 0.f, 0.f);
#pragma unroll
    for (int s = 0; s < 8; s++) {
        int src = (4 * s + rsel) & 15;
        int row = __shfl((s < 4) ? a1 : a2, src, 32);
        float m = __shfl(valid, src, 32);
        float4 v = *(const float4*)&hin[(size_t)row * HID + c * 4];
        acc.x = fmaf(m, v.x, acc.x); acc.y = fmaf(m, v.y, acc.y);
        acc.z = fmaf(m, v.z, acc.z); acc.w = fmaf(m, v.w, acc.w);
    }
#pragma unroll
    for (int mlane = 8; mlane <= 16; mlane <<= 1) {
        acc.x += __shfl_xor(acc.x, mlane, 32);
        acc.y += __shfl_xor(acc.y, mlane, 32);
        acc.z += __shfl_xor(acc.z, mlane, 32);
        acc.w += __shfl_xor(acc.w, mlane, 32);
    }
    float out = 0.f;
#pragma unroll
    for (int k = 0; k < HID; k++) {
        float comp = ((k & 3) == 0) ? acc.x : ((k & 3) == 1) ? acc.y
                   : ((k & 3) == 2) ? acc.z : acc.w;
        out = fmaf(__shfl(comp, k >> 2, 32), Wh[k * HID + j], out);
    }
    agg[(size_t)gid * HID + j] = out;
}

__global__ __launch_bounds__(256) void k_mol(
        const float* __restrict__ h, const int* __restrict__ lsc,
        float* __restrict__ out) {
    int m = blockIdx.x;
    int g = threadIdx.x >> 5;
    int j = threadIdx.x & 31;
    float acc = 0.f;
    for (int i = g; i < MAXATOMS; i += 8) {
        int idx = lsc[m * MAXATOMS + i];
        if (idx > 0) acc += h[(size_t)(idx - 1) * HID + j];
    }
    __shared__ float red[8][33];
    red[g][j] = acc;
    __syncthreads();
    if (g == 0) {
        float s = red[0][j] + red[1][j] + red[2][j] + red[3][j]
                + red[4][j] + red[5][j] + red[6][j] + red[7][j];
        out[m * HID + j] = s;
    }
}

extern "C" void kernel_launch(void* const* d_in, const int* in_sizes, int n_in,
                              void* d_out, int out_size, void* d_ws, size_t ws_size,
                              hipStream_t stream) {
    (void)in_sizes; (void)n_in; (void)out_size;
    const float* tf  = (const float*)d_in[0];
    const float* fdg = (const float*)d_in[1];
    const float* rij = (const float*)d_in[2];
    const int*   bsc = (const int*)d_in[3];
    const int*   lsc = (const int*)d_in[4];
    const int*   su  = (const int*)d_in[5];
    const int*   sul = (const int*)d_in[6];
    const float* Wia = (const float*)d_in[7];
    const float* Wib = (const float*)d_in[8];
    const float* Wh  = (const float*)d_in[9];
    const float* gWz = (const float*)d_in[10];
    const float* gWr = (const float*)d_in[11];
    const float* gWh = (const float*)d_in[12];
    const float* gbz = (const float*)d_in[13];
    const float* gbr = (const float*)d_in[14];
    const float* gbh = (const float*)d_in[15];
    float* out = (float*)d_out;

    char* ws = (char*)d_ws;
    const size_t HBYTES = (size_t)NATOMS * HID * 4;
    const size_t HBFBYTES = ((size_t)(NATOMS + 1) * HID * 2 + 255) & ~(size_t)255;
    const size_t SRCSBYTES = (size_t)NATOMS * 32 * 4;
    const size_t REC16B = (size_t)NPAIRS * 16;
    const size_t REC32B = (size_t)NPAIRS * 32;
    float* h   = (float*)ws;
    float* agg = (float*)(ws + HBYTES);
    ushort_t* hbf = (ushort_t*)(ws + 2 * HBYTES);
    int* srcs = (int*)(ws + 2 * HBYTES + HBFBYTES);
    char* recbase = ws + 2 * HBYTES + HBFBYTES + SRCSBYTES;
    const size_t NEED1 = 2 * HBYTES + HBFBYTES + SRCSBYTES;
    const size_t NEED2 = NEED1 + REC16B;
    const size_t NEED3 = NEED1 + REC32B;
    bool fast   = (ws_size >= NEED1);
    bool rec16  = (ws_size >= NEED2);
    bool rec32  = (ws_size >= NEED3);
    if (!fast) { hbf = nullptr; srcs = nullptr; }

    dim3 igrid(NATOMS / 16);
    dim3 ggrid((NATOMS + 63) / 64);   // k_gru_mfma: 64 atoms/block
    dim3 agrid(NATOMS / 16);
    dim3 afb(NATOMS / 8);

    if (rec32) {
        uint4* rec = (uint4*)recbase;
        k_prep32<<<NPAIRS / 256, 256, 0, stream>>>(fdg, rij, su, sul, rec);
        k_init_rec<<<igrid, 256, 0, stream>>>(tf, bsc, rec, Wia, Wib, Wh,
                                              h, agg, srcs, hbf);
    } else {
        int4* rec = rec16 ? (int4*)recbase : nullptr;
        if (rec16)
            k_prep16<<<NPAIRS / 256, 256, 0, stream>>>(rij, su, sul, rec);
        k_init_legacy<<<igrid, 256, 0, stream>>>(tf, fdg, rij, bsc, su, sul, rec,
                                                 Wia, Wib, Wh, h, agg, srcs, hbf);
    }

    for (int d = 0; d < 3; d++) {
        ushort_t* hbf_w = (fast && d < 2) ? hbf : nullptr;
        k_gru_mfma<<<ggrid, 256, 0, stream>>>(
            h, hbf_w, agg, gWz + d * 2 * HID * HID, gWr + d * 2 * HID * HID,
            gWh + d * 2 * HID * HID, gbz + d * HID, gbr + d * HID, gbh + d * HID);
        if (d < 2) {
            if (fast && rec32)
                k_agg4<<<agrid, 128, 0, stream>>>(hbf, srcs, Wh, agg);
            else if (fast)
                k_agg2<<<agrid, 256, 0, stream>>>(hbf, srcs, Wh, agg);
            else
                k_agg_fb<<<afb, 256, 0, stream>>>(h, bsc, su, sul, Wh, agg);
        }
    }
    k_mol<<<NMOL, 256, 0, stream>>>(h, lsc, out);
}

// Round 9
// 499.792 us; speedup vs baseline: 3.7875x; 1.0831x over previous
//
#include <hip/hip_runtime.h>

#define HID 32
#define NATOMS 250000
#define NPAIRS 4000000
#define MAXNEI 16
#define NMOL 2000
#define MAXATOMS 128
#define FEAT 8

typedef unsigned short ushort_t;
typedef unsigned int uint_t;
typedef short bf16x8 __attribute__((ext_vector_type(8)));
typedef float f32x4 __attribute__((ext_vector_type(4)));

__device__ __forceinline__ float sigmoidf_(float x) { return 1.f / (1.f + __expf(-x)); }
__device__ __forceinline__ float tanhfast_(float x) {
    float e = __expf(2.f * x);
    return 1.f - 2.f / (e + 1.f);
}
__device__ __forceinline__ ushort_t f2bf(float f) {   // RNE
    uint_t u = __float_as_uint(f);
    u = (u + 0x7fffu + ((u >> 16) & 1u)) >> 16;
    return (ushort_t)u;
}
__device__ __forceinline__ float bf2f(ushort_t h) { return __uint_as_float((uint_t)h << 16); }
__device__ __forceinline__ float bflo(uint_t w) { return __uint_as_float(w << 16); }
__device__ __forceinline__ float bfhi(uint_t w) { return __uint_as_float(w & 0xffff0000u); }
// split x into hi+lo bf16 pair (16 effective mantissa bits)
__device__ __forceinline__ void splitbf(float x, short& hi, short& lo) {
    ushort_t h = f2bf(x);
    hi = (short)h;
    lo = (short)f2bf(x - bf2f(h));
}

// ---------- prep: 32B packed record {8xbf16 feats, f32 rij, su, sul, pad} ----------
__global__ __launch_bounds__(256) void k_prep32(
        const float* __restrict__ fdg, const float* __restrict__ rij,
        const int* __restrict__ su, const int* __restrict__ sul,
        uint4* __restrict__ rec) {
    int p = blockIdx.x * 256 + threadIdx.x;   // grid NPAIRS/256 exact
    const float4* f4 = (const float4*)(fdg + (size_t)p * FEAT);
    float4 a = f4[0], b = f4[1];
    uint4 lo;
    lo.x = (uint_t)f2bf(a.x) | ((uint_t)f2bf(a.y) << 16);
    lo.y = (uint_t)f2bf(a.z) | ((uint_t)f2bf(a.w) << 16);
    lo.z = (uint_t)f2bf(b.x) | ((uint_t)f2bf(b.y) << 16);
    lo.w = (uint_t)f2bf(b.z) | ((uint_t)f2bf(b.w) << 16);
    uint4 hi = make_uint4(__float_as_uint(rij[p]), (uint_t)su[p], (uint_t)sul[p], 0u);
    rec[(size_t)p * 2] = lo;
    rec[(size_t)p * 2 + 1] = hi;
}

// ---------- prep: split GRU weights into MFMA B-frag hi/lo planes ----------
// fi = d*12 + mat*4 + nt*2 + kstep ; per (fi,lane): 8 weights -> hi8/lo8 bf16x8.
// wsplit layout: [fi][plane(0=hi,1=lo)][lane][8] ushort  (72 KB total)
__global__ __launch_bounds__(256) void k_prep_w(
        const float* __restrict__ gWz, const float* __restrict__ gWr,
        const float* __restrict__ gWh, ushort_t* __restrict__ wsplit) {
    int t = blockIdx.x * 256 + threadIdx.x;
    if (t >= 36 * 64) return;
    int lane = t & 63;
    int fi = t >> 6;              // 0..35
    int kstep = fi & 1;
    int nt = (fi >> 1) & 1;
    int mat = (fi >> 2) % 3;
    int d = fi / 12;
    const float* W = (mat == 0) ? gWz : (mat == 1) ? gWr : gWh;
    W += d * 2 * HID * HID;
    int g = lane >> 4, cl = lane & 15;
    ushort_t hi8[8], lo8[8];
#pragma unroll
    for (int m = 0; m < 8; m++) {
        float w = W[(kstep * 32 + g * 8 + m) * HID + nt * 16 + cl];
        short th, tl;
        splitbf(w, th, tl);
        hi8[m] = (ushort_t)th;
        lo8[m] = (ushort_t)tl;
    }
    ushort_t* dh = wsplit + ((size_t)fi * 2 + 0) * 512 + lane * 8;
    ushort_t* dl = wsplit + ((size_t)fi * 2 + 1) * 512 + lane * 8;
#pragma unroll
    for (int m = 0; m < 8; m++) { dh[m] = hi8[m]; dl[m] = lo8[m]; }
}

// h0 = tf@Wia ; agg0 = (sum relu(edge@Wib))@Wh from 32B records; builds srcs.
__global__ __launch_bounds__(256) void k_init_rec(
        const float* __restrict__ tf, const int* __restrict__ bsc,
        const uint4* __restrict__ rec,
        const float* __restrict__ Wia, const float* __restrict__ Wib,
        const float* __restrict__ Wh,
        float* __restrict__ h, float* __restrict__ agg,
        int* __restrict__ srcs, ushort_t* __restrict__ hbf) {
    __shared__ float lbuf[8][2][MAXNEI][12];
    int grp = threadIdx.x >> 5;
    int j = threadIdx.x & 31;
    int ja = j >> 4;
    int n = j & 15;
    int gid0 = (blockIdx.x * 8 + grp) * 2;
    int gidja = gid0 + ja;

    int myidx = bsc[gidja * MAXNEI + n];
    int p = (myidx > 0) ? (myidx - 1) : 0;
    float valid = (myidx > 0) ? 1.f : 0.f;

    uint4 lo = rec[(size_t)p * 2];
    uint4 hi = rec[(size_t)p * 2 + 1];

    srcs[(size_t)gidja * 32 + n]      = (myidx > 0) ? (int)hi.y : NATOMS;
    srcs[(size_t)gidja * 32 + 16 + n] = (myidx > 0) ? (int)hi.z : NATOMS;
    if (blockIdx.x == 0 && threadIdx.x < HID)
        hbf[(size_t)NATOMS * HID + threadIdx.x] = 0;

    float* row = lbuf[grp][ja][n];
    row[0] = bflo(lo.x); row[1] = bfhi(lo.x);
    row[2] = bflo(lo.y); row[3] = bfhi(lo.y);
    row[4] = bflo(lo.z); row[5] = bfhi(lo.z);
    row[6] = bflo(lo.w); row[7] = bfhi(lo.w);
    row[8] = __uint_as_float(hi.x);
    row[9] = valid;

    float wib[9];
#pragma unroll
    for (int k = 0; k < 9; k++) wib[k] = Wib[k * HID + j];

    float hj0 = 0.f, hj1 = 0.f;
#pragma unroll
    for (int k = 0; k < FEAT; k++) {
        hj0 = fmaf(tf[(size_t)gid0 * FEAT + k], Wia[k * HID + j], hj0);
        hj1 = fmaf(tf[(size_t)(gid0 + 1) * FEAT + k], Wia[k * HID + j], hj1);
    }

    __syncthreads();

    float aggE[2];
#pragma unroll
    for (int a = 0; a < 2; a++) {
        float e = 0.f;
#pragma unroll
        for (int nn = 0; nn < MAXNEI; nn++) {
            const float* r = lbuf[grp][a][nn];
            float acc = r[8] * wib[8];
#pragma unroll
            for (int k = 0; k < FEAT; k++) acc = fmaf(r[k], wib[k], acc);
            e += r[9] * fmaxf(acc, 0.f);
        }
        aggE[a] = e;
    }

    float o0 = 0.f, o1 = 0.f;
#pragma unroll
    for (int k = 0; k < HID; k++) {
        float wv = Wh[k * HID + j];
        o0 = fmaf(__shfl(aggE[0], k, 32), wv, o0);
        o1 = fmaf(__shfl(aggE[1], k, 32), wv, o1);
    }
    h[(size_t)gid0 * HID + j] = hj0;
    h[(size_t)(gid0 + 1) * HID + j] = hj1;
    agg[(size_t)gid0 * HID + j] = o0;
    agg[(size_t)(gid0 + 1) * HID + j] = o1;
}

// ---------- MFMA GRU, split-bf16 (hi+lo), pre-split B-frags from wsplit ----------
// A layout: lane l holds A[row=l&15][cols 8*(l>>4)..+7]
// B layout: lane l holds B[rows 8*(l>>4)..+7][col=l&15]
// C layout: lane l reg q -> row (l>>4)*4+q, col l&15   [m89-verified]
__global__ __launch_bounds__(256) void k_gru_mfma(
        float* __restrict__ h, ushort_t* __restrict__ hbf,
        const float* __restrict__ agg, const ushort_t* __restrict__ wsp,
        const float* __restrict__ bz, const float* __restrict__ br,
        const float* __restrict__ bh) {
    __shared__ float rhlds[4][16][36];   // fp32 r*h relayout; 9216 B/block
    int wid = threadIdx.x >> 6;
    int l = threadIdx.x & 63;
    int g = l >> 4;                // 0..3
    int cl = l & 15;               // 0..15
    int A0 = blockIdx.x * 64 + wid * 16;

    // --- A-frags (coalesced global), split hi/lo ---
    int rowA = min(A0 + cl, NATOMS - 1);
    const float4* ap = (const float4*)(agg + (size_t)rowA * HID + g * 8);
    float4 fa0 = ap[0], fa1 = ap[1];
    const float4* hp = (const float4*)(h + (size_t)rowA * HID + g * 8);
    float4 fh0 = hp[0], fh1 = hp[1];
    bf16x8 a0h, a0l, a1h, a1l;
    {
        float av[8] = {fa0.x, fa0.y, fa0.z, fa0.w, fa1.x, fa1.y, fa1.z, fa1.w};
        float hv[8] = {fh0.x, fh0.y, fh0.z, fh0.w, fh1.x, fh1.y, fh1.z, fh1.w};
#pragma unroll
        for (int m = 0; m < 8; m++) {
            short th, tl;
            splitbf(av[m], th, tl); a0h[m] = th; a0l[m] = tl;
            splitbf(hv[m], th, tl); a1h[m] = th; a1l[m] = tl;
        }
    }

    // --- h in C layout (for r*h and the (1-z)h term) ---
    int rowC = A0 + g * 4;
    float hC[4][2];
#pragma unroll
    for (int q = 0; q < 4; q++) {
        int r = min(rowC + q, NATOMS - 1);
#pragma unroll
        for (int nt = 0; nt < 2; nt++)
            hC[q][nt] = h[(size_t)r * HID + nt * 16 + cl];
    }

    // --- pre-split B-frag loads: fi = mat*4 + nt*2 + kstep ---
#define LOADW(mat, nt, kstep, dh, dl) { \
        int fi_ = (mat) * 4 + (nt) * 2 + (kstep); \
        dh = *(const bf16x8*)(wsp + ((size_t)fi_ * 2 + 0) * 512 + l * 8); \
        dl = *(const bf16x8*)(wsp + ((size_t)fi_ * 2 + 1) * 512 + l * 8); }
    // 3-product split matmul: ah@bh + ah@bl + al@bh  (~fp32 precision)
#define MM3(ah, al, bh, bl, acc) { \
        acc = __builtin_amdgcn_mfma_f32_16x16x32_bf16(ah, bh, acc, 0, 0, 0); \
        acc = __builtin_amdgcn_mfma_f32_16x16x32_bf16(ah, bl, acc, 0, 0, 0); \
        acc = __builtin_amdgcn_mfma_f32_16x16x32_bf16(al, bh, acc, 0, 0, 0); }

    f32x4 zacc[2], racc[2];
#pragma unroll
    for (int nt = 0; nt < 2; nt++) {
        bf16x8 b0h, b0l, b1h, b1l;
        LOADW(0, nt, 0, b0h, b0l); LOADW(0, nt, 1, b1h, b1l);
        f32x4 acc = {0.f, 0.f, 0.f, 0.f};
        MM3(a0h, a0l, b0h, b0l, acc);
        MM3(a1h, a1l, b1h, b1l, acc);
        zacc[nt] = acc;
        LOADW(1, nt, 0, b0h, b0l); LOADW(1, nt, 1, b1h, b1l);
        f32x4 acc2 = {0.f, 0.f, 0.f, 0.f};
        MM3(a0h, a0l, b0h, b0l, acc2);
        MM3(a1h, a1l, b1h, b1l, acc2);
        racc[nt] = acc2;
    }

    float z[4][2];
#pragma unroll
    for (int nt = 0; nt < 2; nt++) {
        float bzv = bz[nt * 16 + cl];
        float brv = br[nt * 16 + cl];
#pragma unroll
        for (int q = 0; q < 4; q++) {
            z[q][nt] = sigmoidf_(zacc[nt][q] + bzv);
            float rv = sigmoidf_(racc[nt][q] + brv);
            rhlds[wid][g * 4 + q][nt * 16 + cl] = rv * hC[q][nt];   // fp32
        }
    }

    // wave-local LDS RAW: wait our writes, block hoisting of the read
    asm volatile("s_waitcnt lgkmcnt(0)" ::: "memory");
    __builtin_amdgcn_sched_barrier(0);

    bf16x8 a2h, a2l;
    {
        float4 r0 = *(const float4*)&rhlds[wid][cl][g * 8];
        float4 r1 = *(const float4*)&rhlds[wid][cl][g * 8 + 4];
        float rv[8] = {r0.x, r0.y, r0.z, r0.w, r1.x, r1.y, r1.z, r1.w};
#pragma unroll
        for (int m = 0; m < 8; m++) {
            short th, tl;
            splitbf(rv[m], th, tl); a2h[m] = th; a2l[m] = tl;
        }
    }

    f32x4 hcacc[2];
#pragma unroll
    for (int nt = 0; nt < 2; nt++) {
        bf16x8 b0h, b0l, b1h, b1l;
        LOADW(2, nt, 0, b0h, b0l); LOADW(2, nt, 1, b1h, b1l);
        f32x4 acc = {0.f, 0.f, 0.f, 0.f};
        MM3(a0h, a0l, b0h, b0l, acc);
        MM3(a2h, a2l, b1h, b1l, acc);
        hcacc[nt] = acc;
    }
#undef LOADW
#undef MM3

#pragma unroll
    for (int nt = 0; nt < 2; nt++) {
        float bhv = bh[nt * 16 + cl];
#pragma unroll
        for (int q = 0; q < 4; q++) {
            int r = rowC + q;
            if (r < NATOMS) {
                float hc = tanhfast_(hcacc[nt][q] + bhv);
                float zz = z[q][nt];
                float hn = (1.f - zz) * hC[q][nt] + zz * hc;
                h[(size_t)r * HID + nt * 16 + cl] = hn;
                if (hbf) hbf[(size_t)r * HID + nt * 16 + cl] = f2bf(hn);
            }
        }
    }
}

// agg = (sum of 32 gathered bf16 h rows) @ Wh. 4 atoms per 32-lane group,
// 8 groups per 256-thread block (4-wave blocks for occupancy).
__global__ __launch_bounds__(256) void k_agg4(
        const ushort_t* __restrict__ hbf, const int* __restrict__ srcs,
        const float* __restrict__ Wh, float* __restrict__ agg) {
    int grp = threadIdx.x >> 5;
    int j = threadIdx.x & 31;
    int gid0 = (blockIdx.x * 8 + grp) * 4;
    if (gid0 >= NATOMS) return;   // no __syncthreads in kernel

    int s[4];
#pragma unroll
    for (int a = 0; a < 4; a++) s[a] = srcs[(size_t)(gid0 + a) * 32 + j];

    int rslot = j >> 2;
    int c = j & 3;

    uint4 v[4][4];
#pragma unroll
    for (int a = 0; a < 4; a++)
#pragma unroll
        for (int sw = 0; sw < 4; sw++) {
            int r = __shfl(s[a], sw * 8 + rslot, 32);
            v[a][sw] = ((const uint4*)(hbf + (size_t)r * HID))[c];
        }

    float acc[4][8];
#pragma unroll
    for (int a = 0; a < 4; a++)
#pragma unroll
        for (int e = 0; e < 8; e++) acc[a][e] = 0.f;
#pragma unroll
    for (int a = 0; a < 4; a++)
#pragma unroll
        for (int sw = 0; sw < 4; sw++) {
            const uint_t* u = (const uint_t*)&v[a][sw];
#pragma unroll
            for (int e = 0; e < 8; e++)
                acc[a][e] += (e & 1) ? bfhi(u[e >> 1]) : bflo(u[e >> 1]);
        }
#pragma unroll
    for (int m = 4; m <= 16; m <<= 1)
#pragma unroll
        for (int a = 0; a < 4; a++)
#pragma unroll
            for (int e = 0; e < 8; e++) acc[a][e] += __shfl_xor(acc[a][e], m, 32);

    float o[4] = {0.f, 0.f, 0.f, 0.f};
#pragma unroll
    for (int k = 0; k < HID; k++) {
        float wv = Wh[k * HID + j];
#pragma unroll
        for (int a = 0; a < 4; a++)
            o[a] = fmaf(__shfl(acc[a][k & 7], k >> 3, 32), wv, o[a]);
    }
#pragma unroll
    for (int a = 0; a < 4; a++) agg[(size_t)(gid0 + a) * HID + j] = o[a];
}

__global__ __launch_bounds__(256) void k_mol(
        const float* __restrict__ h, const int* __restrict__ lsc,
        float* __restrict__ out) {
    int m = blockIdx.x;
    int g = threadIdx.x >> 5;
    int j = threadIdx.x & 31;
    float acc = 0.f;
    for (int i = g; i < MAXATOMS; i += 8) {
        int idx = lsc[m * MAXATOMS + i];
        if (idx > 0) acc += h[(size_t)(idx - 1) * HID + j];
    }
    __shared__ float red[8][33];
    red[g][j] = acc;
    __syncthreads();
    if (g == 0) {
        float s = red[0][j] + red[1][j] + red[2][j] + red[3][j]
                + red[4][j] + red[5][j] + red[6][j] + red[7][j];
        out[m * HID + j] = s;
    }
}

extern "C" void kernel_launch(void* const* d_in, const int* in_sizes, int n_in,
                              void* d_out, int out_size, void* d_ws, size_t ws_size,
                              hipStream_t stream) {
    (void)in_sizes; (void)n_in; (void)out_size; (void)ws_size;
    const float* tf  = (const float*)d_in[0];
    const float* fdg = (const float*)d_in[1];
    const float* rij = (const float*)d_in[2];
    const int*   bsc = (const int*)d_in[3];
    const int*   lsc = (const int*)d_in[4];
    const int*   su  = (const int*)d_in[5];
    const int*   sul = (const int*)d_in[6];
    const float* Wia = (const float*)d_in[7];
    const float* Wib = (const float*)d_in[8];
    const float* Wh  = (const float*)d_in[9];
    const float* gWz = (const float*)d_in[10];
    const float* gWr = (const float*)d_in[11];
    const float* gWh = (const float*)d_in[12];
    const float* gbz = (const float*)d_in[13];
    const float* gbr = (const float*)d_in[14];
    const float* gbh = (const float*)d_in[15];
    float* out = (float*)d_out;

    char* ws = (char*)d_ws;
    const size_t HBYTES = (size_t)NATOMS * HID * 4;                   // 32 MB
    const size_t WSPLITB = 36 * 2 * 512 * 2;                          // 72 KB
    const size_t HBFBYTES = ((size_t)(NATOMS + 1) * HID * 2 + 255) & ~(size_t)255;
    const size_t SRCSBYTES = (size_t)NATOMS * 32 * 4;                 // 32 MB
    float* h   = (float*)ws;
    float* agg = (float*)(ws + HBYTES);
    ushort_t* wsplit = (ushort_t*)(ws + 2 * HBYTES);
    ushort_t* hbf = (ushort_t*)(ws + 2 * HBYTES + WSPLITB);
    int* srcs = (int*)(ws + 2 * HBYTES + WSPLITB + HBFBYTES);
    uint4* rec = (uint4*)(ws + 2 * HBYTES + WSPLITB + HBFBYTES + SRCSBYTES);

    dim3 igrid(NATOMS / 16);                   // 15625
    dim3 ggrid((NATOMS + 63) / 64);            // 3907
    dim3 agrid((NATOMS / 4 + 7) / 8);          // 7813

    k_prep32<<<NPAIRS / 256, 256, 0, stream>>>(fdg, rij, su, sul, rec);
    k_prep_w<<<9, 256, 0, stream>>>(gWz, gWr, gWh, wsplit);
    k_init_rec<<<igrid, 256, 0, stream>>>(tf, bsc, rec, Wia, Wib, Wh,
                                          h, agg, srcs, hbf);

    for (int d = 0; d < 3; d++) {
        ushort_t* hbf_w = (d < 2) ? hbf : nullptr;
        k_gru_mfma<<<ggrid, 256, 0, stream>>>(
            h, hbf_w, agg, wsplit + (size_t)d * 12288,
            gbz + d * HID, gbr + d * HID, gbh + d * HID);
        if (d < 2)
            k_agg4<<<agrid, 256, 0, stream>>>(hbf, srcs, Wh, agg);
    }
    k_mol<<<NMOL, 256, 0, stream>>>(h, lsc, out);
}